// Round 4
// baseline (1807.856 us; speedup 1.0000x reference)
//
#include <hip/hip_runtime.h>
#include <cstddef>
#include <cstdint>
#include <cmath>

#define D_MODEL 2048
#define DICT    32768
#define KTOP    32
#define NROWS   2048
#define NCAND_MIN 56        // candidate margin over KTOP (guards bf16 error)
#define CAPMAX  256
#define KSTEPS  (D_MODEL / 32)      // 64
#define TM      (NROWS / 128)       // 16
#define TN      (DICT / 128)        // 256

typedef float    f32x4  __attribute__((ext_vector_type(4)));
typedef __bf16   bf16x8 __attribute__((ext_vector_type(8)));
typedef unsigned short us8 __attribute__((ext_vector_type(8)));

__device__ __forceinline__ unsigned short f2bf_rne(float f) {
    unsigned u = __builtin_bit_cast(unsigned, f);
    unsigned r = u + 0x7fffu + ((u >> 16) & 1u);
    return (unsigned short)(r >> 16);
}

__device__ __forceinline__ void gload16(const void* g, const void* s) {
    __builtin_amdgcn_global_load_lds(
        (const __attribute__((address_space(1))) unsigned int*)g,
        (__attribute__((address_space(3))) unsigned int*)s, 16, 0, 0);
}

// ---------------------------------------------------------------------------
// Convert x and We f32 -> bf16, pre-tiled [tile][kstep][128 rows][32 k] with
// XOR swizzle baked in (byte ^= (row&7)<<4 within each 8KB k-step tile), so
// the GEMM can global_load_lds linearly and ds_read conflict-free.
// One thread = one (row, kstep) pair = 32 elements (128B read, 64B write).
// ---------------------------------------------------------------------------
__global__ __launch_bounds__(256) void convert_tiles(
    const float* __restrict__ x,          // [NROWS][D_MODEL]
    const float* __restrict__ We,         // [DICT][D_MODEL]
    unsigned short* __restrict__ xbf,     // [TM][KSTEPS][4096] ushorts
    unsigned short* __restrict__ webf)    // [TN][KSTEPS][4096] ushorts
{
    const size_t NX = (size_t)NROWS * KSTEPS;
    size_t id = (size_t)blockIdx.x * 256 + threadIdx.x;

    const float* src;
    unsigned short* dst;
    int r;
    if (id < NX) {
        const int row = (int)(id >> 6), s = (int)(id & 63);
        src = x + (size_t)row * D_MODEL + s * 32;
        r = row & 127;
        dst = xbf + ((size_t)((row >> 7) * KSTEPS + s)) * 4096;
    } else {
        id -= NX;
        const int row = (int)(id >> 6), s = (int)(id & 63);
        src = We + (size_t)row * D_MODEL + s * 32;
        r = row & 127;
        dst = webf + ((size_t)((row >> 7) * KSTEPS + s)) * 4096;
    }

    #pragma unroll
    for (int qc = 0; qc < 4; ++qc) {
        float4 v0 = reinterpret_cast<const float4*>(src)[qc * 2];
        float4 v1 = reinterpret_cast<const float4*>(src)[qc * 2 + 1];
        us8 c;
        c[0] = f2bf_rne(v0.x); c[1] = f2bf_rne(v0.y);
        c[2] = f2bf_rne(v0.z); c[3] = f2bf_rne(v0.w);
        c[4] = f2bf_rne(v1.x); c[5] = f2bf_rne(v1.y);
        c[6] = f2bf_rne(v1.z); c[7] = f2bf_rne(v1.w);
        const int byteoff = (r * 64 + qc * 16) ^ ((r & 7) << 4);
        *reinterpret_cast<us8*>(reinterpret_cast<char*>(dst) + byteoff) = c;
    }
}

// ---------------------------------------------------------------------------
// Encoder GEMM, pure bf16 (m97 structure): 128x128 tile, BK=32, 4 waves 2x2,
// global_load_lds width=16 into double-buffered linear LDS (sources are
// pre-swizzled), 16 MFMA + 8 ds_read_b128 per K-step, 2-barrier loop.
// ---------------------------------------------------------------------------
__global__ __launch_bounds__(256) void encoder_bf16(
    const unsigned short* __restrict__ xbf,   // tiled+swz
    const unsigned short* __restrict__ webf,  // tiled+swz
    const float* __restrict__ bias,
    float* __restrict__ C)                    // pre [NROWS][DICT]
{
    __shared__ __align__(16) unsigned short Abuf[2][4096];   // 8KB each
    __shared__ __align__(16) unsigned short Bbuf[2][4096];

    const int t    = threadIdx.x;
    const int lane = t & 63;
    const int w    = t >> 6;
    const int wr   = w >> 1;
    const int wc   = w & 1;

    // XCD-bijective swizzle (4096 % 8 == 0); consecutive swz share B panel
    const int bid = blockIdx.x;
    const int swz = (bid & 7) * (TM * TN / 8) + (bid >> 3);
    const int mt  = swz & (TM - 1);
    const int nt  = swz >> 4;

    const char* Asrc = (const char*)(xbf  + (size_t)mt * KSTEPS * 4096);
    const char* Bsrc = (const char*)(webf + (size_t)nt * KSTEPS * 4096);

    f32x4 acc[4][4];
    #pragma unroll
    for (int i = 0; i < 4; ++i)
        #pragma unroll
        for (int j = 0; j < 4; ++j) acc[i][j] = (f32x4)0.f;

    const int lchunk = w * 1024 + lane * 16;   // byte offset of this lane's chunk

    #define STAGE(buf, kt) do {                                              \
        const char* a_ = Asrc + (size_t)(kt) * 8192;                         \
        const char* b_ = Bsrc + (size_t)(kt) * 8192;                         \
        gload16(a_ + lchunk,        &Abuf[buf][w * 512]);                    \
        gload16(a_ + lchunk + 4096, &Abuf[buf][w * 512 + 2048]);             \
        gload16(b_ + lchunk,        &Bbuf[buf][w * 512]);                    \
        gload16(b_ + lchunk + 4096, &Bbuf[buf][w * 512 + 2048]);             \
    } while (0)

    STAGE(0, 0);
    __syncthreads();

    const int q16 = (lane >> 4) * 16;   // k-slice byte offset
    int cur = 0;
    for (int kt = 0; kt < KSTEPS; ++kt) {
        if (kt + 1 < KSTEPS) STAGE(cur ^ 1, kt + 1);

        bf16x8 fa[4], fb[4];
        #pragma unroll
        for (int i = 0; i < 4; ++i) {
            const int row = wr * 64 + i * 16 + (lane & 15);
            const int off = ((row * 64 + q16) ^ ((row & 7) << 4)) >> 1;
            fa[i] = __builtin_bit_cast(bf16x8,
                *reinterpret_cast<const us8*>(&Abuf[cur][off]));
        }
        #pragma unroll
        for (int j = 0; j < 4; ++j) {
            const int row = wc * 64 + j * 16 + (lane & 15);
            const int off = ((row * 64 + q16) ^ ((row & 7) << 4)) >> 1;
            fb[j] = __builtin_bit_cast(bf16x8,
                *reinterpret_cast<const us8*>(&Bbuf[cur][off]));
        }
        #pragma unroll
        for (int i = 0; i < 4; ++i)
            #pragma unroll
            for (int j = 0; j < 4; ++j)
                acc[i][j] = __builtin_amdgcn_mfma_f32_16x16x32_bf16(
                    fa[i], fb[j], acc[i][j], 0, 0, 0);

        __syncthreads();
        cur ^= 1;
    }
    #undef STAGE

    const int m0 = mt * 128, n0 = nt * 128;
    #pragma unroll
    for (int j = 0; j < 4; ++j) {
        const int col = n0 + wc * 64 + j * 16 + (lane & 15);
        const float bv = bias[col];
        #pragma unroll
        for (int i = 0; i < 4; ++i) {
            const int rowb = m0 + wr * 64 + i * 16 + ((lane >> 4) * 4);
            #pragma unroll
            for (int r = 0; r < 4; ++r)
                C[(size_t)(rowb + r) * DICT + col] = acc[i][j][r] + bv;
        }
    }
}

// ---------------------------------------------------------------------------
// Histogram radix-select of positive candidates. One block per row.
// ---------------------------------------------------------------------------
__global__ __launch_bounds__(256) void topk_cand_hist(
    const float* __restrict__ pre,
    int* __restrict__ cand_idx,
    int* __restrict__ cand_cnt,
    int cap)
{
    __shared__ unsigned hist[4096];
    __shared__ unsigned part[2][256];
    __shared__ int s_thr;
    __shared__ unsigned s_cnt;

    const int n = blockIdx.x;
    const int t = threadIdx.x;
    const float4* src = reinterpret_cast<const float4*>(pre + (size_t)n * DICT);

    for (int i = t; i < 4096; i += 256) hist[i] = 0;
    if (t == 0) { s_thr = -1; s_cnt = 0; }
    __syncthreads();

    #pragma unroll 4
    for (int p = 0; p < DICT / 1024; ++p) {
        float4 v = src[t + 256 * p];
        float e[4] = {v.x, v.y, v.z, v.w};
        #pragma unroll
        for (int j = 0; j < 4; ++j)
            if (e[j] > 0.f)
                atomicAdd(&hist[__builtin_bit_cast(unsigned, e[j]) >> 19], 1u);
    }
    __syncthreads();

    unsigned hv[16];
    unsigned local = 0;
    #pragma unroll
    for (int b = 0; b < 16; ++b) { hv[b] = hist[t * 16 + b]; local += hv[b]; }
    part[0][t] = local;
    __syncthreads();
    int sb = 0;
    for (int s = 1; s < 256; s <<= 1) {
        unsigned v2 = part[sb][t];
        if (t + s < 256) v2 += part[sb][t + s];
        part[sb ^ 1][t] = v2;
        sb ^= 1;
        __syncthreads();
    }
    const unsigned above = (t < 255) ? part[sb][t + 1] : 0;

    unsigned cum = above;
    int mybin = -1;
    #pragma unroll
    for (int b = 15; b >= 0; --b) {
        cum += hv[b];
        if (mybin < 0 && cum >= NCAND_MIN) mybin = t * 16 + b;
    }
    if (mybin >= 0) atomicMax(&s_thr, mybin);
    __syncthreads();
    const unsigned thr = (s_thr < 0) ? 0u : (unsigned)s_thr;

    for (int p = 0; p < DICT / 1024; ++p) {
        float4 v = src[t + 256 * p];
        float e[4] = {v.x, v.y, v.z, v.w};
        #pragma unroll
        for (int j = 0; j < 4; ++j) {
            if (e[j] > 0.f &&
                (__builtin_bit_cast(unsigned, e[j]) >> 19) >= thr) {
                unsigned pos = atomicAdd(&s_cnt, 1u);
                if (pos < (unsigned)cap)
                    cand_idx[(size_t)n * cap + pos] = (t + 256 * p) * 4 + j;
            }
        }
    }
    __syncthreads();
    if (t == 0) cand_cnt[n] = (int)min(s_cnt, (unsigned)cap);
}

// ---------------------------------------------------------------------------
// Exact f32 recompute of candidate dots + exact top-32 + relu + scatter.
// ---------------------------------------------------------------------------
__global__ __launch_bounds__(256) void recompute_select_kernel(
    const float* __restrict__ x,
    const float* __restrict__ We,
    const float* __restrict__ be,
    const int*   __restrict__ cand_idx,
    const int*   __restrict__ cand_cnt,
    int cap,
    float* __restrict__ features,
    float* __restrict__ vals_out,
    int*   __restrict__ idx_out)
{
    __shared__ float xr[D_MODEL];
    __shared__ float cv[CAPMAX];
    __shared__ int   ci[CAPMAX];

    const int n    = blockIdx.x;
    const int t    = threadIdx.x;
    const int lane = t & 63;
    const int w    = t >> 6;
    const int cnt  = cand_cnt[n];

    for (int i = t; i < D_MODEL / 4; i += 256)
        reinterpret_cast<float4*>(xr)[i] =
            reinterpret_cast<const float4*>(x + (size_t)n * D_MODEL)[i];
    for (int c = t; c < cnt; c += 256) ci[c] = cand_idx[(size_t)n * cap + c];
    __syncthreads();

    for (int c = w; c < cnt; c += 4) {
        const int idx = ci[c];
        const float4* wrow = reinterpret_cast<const float4*>(We + (size_t)idx * D_MODEL);
        const float4* xro  = reinterpret_cast<const float4*>(xr);
        float s = 0.f;
        #pragma unroll
        for (int p = 0; p < 8; ++p) {
            float4 a = xro[lane + 64 * p];
            float4 b = wrow[lane + 64 * p];
            s = fmaf(a.x, b.x, s); s = fmaf(a.y, b.y, s);
            s = fmaf(a.z, b.z, s); s = fmaf(a.w, b.w, s);
        }
        #pragma unroll
        for (int sh = 1; sh < 64; sh <<= 1) s += __shfl_xor(s, sh);
        if (lane == 0) cv[c] = s + be[idx];
    }
    __syncthreads();

    if (w == 0) {
        float pv[CAPMAX / 64];
        int   pi[CAPMAX / 64];
        #pragma unroll
        for (int qq = 0; qq < CAPMAX / 64; ++qq) {
            const int c = lane + 64 * qq;
            const bool ok = c < cnt;
            pv[qq] = ok ? cv[c] : -INFINITY;
            pi[qq] = ok ? ci[c] : 0x7fffffff;
        }
        for (int r = 0; r < KTOP; ++r) {
            float bv = pv[0]; int bi = pi[0]; int bq = 0;
            #pragma unroll
            for (int qq = 1; qq < CAPMAX / 64; ++qq)
                if (pv[qq] > bv || (pv[qq] == bv && pi[qq] < bi)) {
                    bv = pv[qq]; bi = pi[qq]; bq = qq;
                }
            float gv = bv; int gi = bi;
            #pragma unroll
            for (int s = 1; s < 64; s <<= 1) {
                float ov = __shfl_xor(gv, s);
                int   oi = __shfl_xor(gi, s);
                if (ov > gv || (ov == gv && oi < gi)) { gv = ov; gi = oi; }
            }
            if (bi == gi) pv[bq] = -INFINITY;
            if (lane == 0) {
                const bool valid = (gi != 0x7fffffff);
                const float rv = (valid && gv > 0.f) ? gv : 0.f;
                vals_out[n * KTOP + r] = rv;
                idx_out[n * KTOP + r]  = valid ? gi : 0;
                if (valid) features[(size_t)n * DICT + gi] = rv;
            }
        }
    }
}

// ---------------------------------------------------------------------------
// Decoder: 2-pass over Wd-row halves (64KB LDS -> 2 blocks/CU).
// ---------------------------------------------------------------------------
__global__ __launch_bounds__(256) void decoder_kernel(
    const float* __restrict__ Wd,
    const float* __restrict__ bd,
    const float* __restrict__ vals,
    const int*   __restrict__ idxs,
    float* __restrict__ recon)
{
    __shared__ float wrow[DICT / 2];
    const int d = blockIdx.x;
    const int t = threadIdx.x;

    float accs[NROWS / 256];
    #pragma unroll
    for (int u = 0; u < NROWS / 256; ++u) accs[u] = 0.f;

    for (int h = 0; h < 2; ++h) {
        __syncthreads();
        const float* src = Wd + (size_t)d * DICT + h * (DICT / 2);
        for (int i = t; i < DICT / 8; i += 256)
            reinterpret_cast<float4*>(wrow)[i] =
                reinterpret_cast<const float4*>(src)[i];
        __syncthreads();
        const int base = h * (DICT / 2);
        #pragma unroll
        for (int u = 0; u < NROWS / 256; ++u) {
            const int n = t + 256 * u;
            const float* v  = vals + n * KTOP;
            const int*   ix = idxs + n * KTOP;
            float a = accs[u];
            #pragma unroll
            for (int k = 0; k < KTOP; ++k) {
                const unsigned rel = (unsigned)(ix[k] - base);
                if (rel < (unsigned)(DICT / 2)) a = fmaf(v[k], wrow[rel], a);
            }
            accs[u] = a;
        }
    }
    const float b = bd[d];
    #pragma unroll
    for (int u = 0; u < NROWS / 256; ++u)
        recon[(size_t)(t + 256 * u) * D_MODEL + d] = accs[u] + b;
}

// ---------------------------------------------------------------------------
extern "C" void kernel_launch(void* const* d_in, const int* in_sizes, int n_in,
                              void* d_out, int out_size, void* d_ws, size_t ws_size,
                              hipStream_t stream)
{
    const float* x  = (const float*)d_in[0];
    const float* We = (const float*)d_in[1];
    const float* be = (const float*)d_in[2];
    const float* Wd = (const float*)d_in[3];
    const float* bd = (const float*)d_in[4];

    float* out      = (float*)d_out;
    float* recon    = out;
    float* features = out + (size_t)NROWS * D_MODEL;
    float* pre      = features + (size_t)NROWS * DICT;

    // bf16 tiled operands parked in the features region (memset'd after GEMM)
    unsigned short* webf = (unsigned short*)features;                 // 128 MB
    unsigned short* xbf  = webf + (size_t)TN * KSTEPS * 4096;         // + 8 MB

    long cap_l = (long)(ws_size / 4 - (size_t)NROWS * (1 + 2 * KTOP)) / NROWS;
    int cap = (int)(cap_l < 64 ? 64 : (cap_l > CAPMAX ? CAPMAX : cap_l));

    char* ws = (char*)d_ws;
    int*   ws_cand = (int*)ws;
    int*   ws_cnt  = (int*)(ws + (size_t)NROWS * cap * 4);
    float* ws_vals = (float*)(ws + (size_t)NROWS * (cap + 1) * 4);
    int*   ws_idx  = (int*)(ws + (size_t)NROWS * (cap + 1 + KTOP) * 4);

    // 1) convert + tile + swizzle operands to bf16
    const int conv_blocks = (int)(((size_t)NROWS * KSTEPS + (size_t)DICT * KSTEPS) / 256);
    convert_tiles<<<conv_blocks, 256, 0, stream>>>(x, We, xbf, webf);

    // 2) encoder GEMM (pure bf16, m97 structure) -> approx pre_acts
    encoder_bf16<<<TM * TN, 256, 0, stream>>>(xbf, webf, be, pre);

    // 3) zero dense features (also wipes the bf16 staging)
    hipMemsetAsync(features, 0, (size_t)NROWS * DICT * sizeof(float), stream);

    // 4) positive-value histogram candidates
    topk_cand_hist<<<NROWS, 256, 0, stream>>>(pre, ws_cand, ws_cnt, cap);

    // 5) exact recompute + exact top-32 + scatter
    recompute_select_kernel<<<NROWS, 256, 0, stream>>>(
        x, We, be, ws_cand, ws_cnt, cap, features, ws_vals, ws_idx);

    // 6) sparse decoder
    decoder_kernel<<<D_MODEL, 256, 0, stream>>>(Wd, bd, ws_vals, ws_idx, recon);
}

// Round 5
// 1203.583 us; speedup vs baseline: 1.5021x; 1.5021x over previous
//
#include <hip/hip_runtime.h>
#include <cstddef>
#include <cstdint>
#include <cmath>

#define D_MODEL 2048
#define DICT    32768
#define KTOP    32
#define NROWS   2048
#define NCAND_MIN 56        // candidate margin over KTOP (guards bf16 error)
#define CAPMAX  256
#define KSTEPS  (D_MODEL / 32)      // 64
#define TM      (NROWS / 128)       // 16
#define TN      (DICT / 128)        // 256

typedef float    f32x4  __attribute__((ext_vector_type(4)));
typedef __bf16   bf16x8 __attribute__((ext_vector_type(8)));
typedef unsigned short us8 __attribute__((ext_vector_type(8)));

__device__ __forceinline__ unsigned short f2bf_rne(float f) {
    unsigned u = __builtin_bit_cast(unsigned, f);
    unsigned r = u + 0x7fffu + ((u >> 16) & 1u);
    return (unsigned short)(r >> 16);
}

__device__ __forceinline__ void gload16(const void* g, const void* s) {
    __builtin_amdgcn_global_load_lds(
        (const __attribute__((address_space(1))) unsigned int*)g,
        (__attribute__((address_space(3))) unsigned int*)s, 16, 0, 0);
}

// ---------------------------------------------------------------------------
// Convert x and We f32 -> bf16, pre-tiled [tile][kstep][128 rows][32 k] with
// XOR swizzle baked in (byte ^= (row&7)<<4 within each 8KB k-step tile).
// ---------------------------------------------------------------------------
__global__ __launch_bounds__(256) void convert_tiles(
    const float* __restrict__ x,
    const float* __restrict__ We,
    unsigned short* __restrict__ xbf,     // [TM][KSTEPS][4096] ushorts
    unsigned short* __restrict__ webf)    // [TN][KSTEPS][4096] ushorts
{
    const size_t NX = (size_t)NROWS * KSTEPS;
    size_t id = (size_t)blockIdx.x * 256 + threadIdx.x;

    const float* src;
    unsigned short* dst;
    int r;
    if (id < NX) {
        const int row = (int)(id >> 6), s = (int)(id & 63);
        src = x + (size_t)row * D_MODEL + s * 32;
        r = row & 127;
        dst = xbf + ((size_t)((row >> 7) * KSTEPS + s)) * 4096;
    } else {
        id -= NX;
        const int row = (int)(id >> 6), s = (int)(id & 63);
        src = We + (size_t)row * D_MODEL + s * 32;
        r = row & 127;
        dst = webf + ((size_t)((row >> 7) * KSTEPS + s)) * 4096;
    }

    #pragma unroll
    for (int qc = 0; qc < 4; ++qc) {
        float4 v0 = reinterpret_cast<const float4*>(src)[qc * 2];
        float4 v1 = reinterpret_cast<const float4*>(src)[qc * 2 + 1];
        us8 c;
        c[0] = f2bf_rne(v0.x); c[1] = f2bf_rne(v0.y);
        c[2] = f2bf_rne(v0.z); c[3] = f2bf_rne(v0.w);
        c[4] = f2bf_rne(v1.x); c[5] = f2bf_rne(v1.y);
        c[6] = f2bf_rne(v1.z); c[7] = f2bf_rne(v1.w);
        const int byteoff = (r * 64 + qc * 16) ^ ((r & 7) << 4);
        *reinterpret_cast<us8*>(reinterpret_cast<char*>(dst) + byteoff) = c;
    }
}

// ---------------------------------------------------------------------------
// Encoder GEMM, pure bf16 (m97 structure).
// ---------------------------------------------------------------------------
__global__ __launch_bounds__(256) void encoder_bf16(
    const unsigned short* __restrict__ xbf,
    const unsigned short* __restrict__ webf,
    const float* __restrict__ bias,
    float* __restrict__ C)
{
    __shared__ __align__(16) unsigned short Abuf[2][4096];
    __shared__ __align__(16) unsigned short Bbuf[2][4096];

    const int t    = threadIdx.x;
    const int lane = t & 63;
    const int w    = t >> 6;
    const int wr   = w >> 1;
    const int wc   = w & 1;

    const int bid = blockIdx.x;
    const int swz = (bid & 7) * (TM * TN / 8) + (bid >> 3);
    const int mt  = swz & (TM - 1);
    const int nt  = swz >> 4;

    const char* Asrc = (const char*)(xbf  + (size_t)mt * KSTEPS * 4096);
    const char* Bsrc = (const char*)(webf + (size_t)nt * KSTEPS * 4096);

    f32x4 acc[4][4];
    #pragma unroll
    for (int i = 0; i < 4; ++i)
        #pragma unroll
        for (int j = 0; j < 4; ++j) acc[i][j] = (f32x4)0.f;

    const int lchunk = w * 1024 + lane * 16;

    #define STAGE(buf, kt) do {                                              \
        const char* a_ = Asrc + (size_t)(kt) * 8192;                         \
        const char* b_ = Bsrc + (size_t)(kt) * 8192;                         \
        gload16(a_ + lchunk,        &Abuf[buf][w * 512]);                    \
        gload16(a_ + lchunk + 4096, &Abuf[buf][w * 512 + 2048]);             \
        gload16(b_ + lchunk,        &Bbuf[buf][w * 512]);                    \
        gload16(b_ + lchunk + 4096, &Bbuf[buf][w * 512 + 2048]);             \
    } while (0)

    STAGE(0, 0);
    __syncthreads();

    const int q16 = (lane >> 4) * 16;
    int cur = 0;
    for (int kt = 0; kt < KSTEPS; ++kt) {
        if (kt + 1 < KSTEPS) STAGE(cur ^ 1, kt + 1);

        bf16x8 fa[4], fb[4];
        #pragma unroll
        for (int i = 0; i < 4; ++i) {
            const int row = wr * 64 + i * 16 + (lane & 15);
            const int off = ((row * 64 + q16) ^ ((row & 7) << 4)) >> 1;
            fa[i] = __builtin_bit_cast(bf16x8,
                *reinterpret_cast<const us8*>(&Abuf[cur][off]));
        }
        #pragma unroll
        for (int j = 0; j < 4; ++j) {
            const int row = wc * 64 + j * 16 + (lane & 15);
            const int off = ((row * 64 + q16) ^ ((row & 7) << 4)) >> 1;
            fb[j] = __builtin_bit_cast(bf16x8,
                *reinterpret_cast<const us8*>(&Bbuf[cur][off]));
        }
        #pragma unroll
        for (int i = 0; i < 4; ++i)
            #pragma unroll
            for (int j = 0; j < 4; ++j)
                acc[i][j] = __builtin_amdgcn_mfma_f32_16x16x32_bf16(
                    fa[i], fb[j], acc[i][j], 0, 0, 0);

        __syncthreads();
        cur ^= 1;
    }
    #undef STAGE

    const int m0 = mt * 128, n0 = nt * 128;
    #pragma unroll
    for (int j = 0; j < 4; ++j) {
        const int col = n0 + wc * 64 + j * 16 + (lane & 15);
        const float bv = bias[col];
        #pragma unroll
        for (int i = 0; i < 4; ++i) {
            const int rowb = m0 + wr * 64 + i * 16 + ((lane >> 4) * 4);
            #pragma unroll
            for (int r = 0; r < 4; ++r)
                C[(size_t)(rowb + r) * DICT + col] = acc[i][j][r] + bv;
        }
    }
}

// ---------------------------------------------------------------------------
// Histogram radix-select of positive candidates. One block per row.
// ---------------------------------------------------------------------------
__global__ __launch_bounds__(256) void topk_cand_hist(
    const float* __restrict__ pre,
    int* __restrict__ cand_idx,
    int* __restrict__ cand_cnt,
    int cap)
{
    __shared__ unsigned hist[4096];
    __shared__ unsigned part[2][256];
    __shared__ int s_thr;
    __shared__ unsigned s_cnt;

    const int n = blockIdx.x;
    const int t = threadIdx.x;
    const float4* src = reinterpret_cast<const float4*>(pre + (size_t)n * DICT);

    for (int i = t; i < 4096; i += 256) hist[i] = 0;
    if (t == 0) { s_thr = -1; s_cnt = 0; }
    __syncthreads();

    #pragma unroll 4
    for (int p = 0; p < DICT / 1024; ++p) {
        float4 v = src[t + 256 * p];
        float e[4] = {v.x, v.y, v.z, v.w};
        #pragma unroll
        for (int j = 0; j < 4; ++j)
            if (e[j] > 0.f)
                atomicAdd(&hist[__builtin_bit_cast(unsigned, e[j]) >> 19], 1u);
    }
    __syncthreads();

    unsigned hv[16];
    unsigned local = 0;
    #pragma unroll
    for (int b = 0; b < 16; ++b) { hv[b] = hist[t * 16 + b]; local += hv[b]; }
    part[0][t] = local;
    __syncthreads();
    int sb = 0;
    for (int s = 1; s < 256; s <<= 1) {
        unsigned v2 = part[sb][t];
        if (t + s < 256) v2 += part[sb][t + s];
        part[sb ^ 1][t] = v2;
        sb ^= 1;
        __syncthreads();
    }
    const unsigned above = (t < 255) ? part[sb][t + 1] : 0;

    unsigned cum = above;
    int mybin = -1;
    #pragma unroll
    for (int b = 15; b >= 0; --b) {
        cum += hv[b];
        if (mybin < 0 && cum >= NCAND_MIN) mybin = t * 16 + b;
    }
    if (mybin >= 0) atomicMax(&s_thr, mybin);
    __syncthreads();
    const unsigned thr = (s_thr < 0) ? 0u : (unsigned)s_thr;

    for (int p = 0; p < DICT / 1024; ++p) {
        float4 v = src[t + 256 * p];
        float e[4] = {v.x, v.y, v.z, v.w};
        #pragma unroll
        for (int j = 0; j < 4; ++j) {
            if (e[j] > 0.f &&
                (__builtin_bit_cast(unsigned, e[j]) >> 19) >= thr) {
                unsigned pos = atomicAdd(&s_cnt, 1u);
                if (pos < (unsigned)cap)
                    cand_idx[(size_t)n * cap + pos] = (t + 256 * p) * 4 + j;
            }
        }
    }
    __syncthreads();
    if (t == 0) cand_cnt[n] = (int)min(s_cnt, (unsigned)cap);
}

// ---------------------------------------------------------------------------
// Exact f32 recompute + exact top-32 + relu + scatter.
// Writes vals/idx in TRANSPOSED [KTOP][NROWS] layout for coalesced decoder.
// ---------------------------------------------------------------------------
__global__ __launch_bounds__(256) void recompute_select_kernel(
    const float* __restrict__ x,
    const float* __restrict__ We,
    const float* __restrict__ be,
    const int*   __restrict__ cand_idx,
    const int*   __restrict__ cand_cnt,
    int cap,
    float* __restrict__ features,
    float* __restrict__ valsT,           // [KTOP][NROWS]
    int*   __restrict__ idxT)            // [KTOP][NROWS]
{
    __shared__ float xr[D_MODEL];
    __shared__ float cv[CAPMAX];
    __shared__ int   ci[CAPMAX];

    const int n    = blockIdx.x;
    const int t    = threadIdx.x;
    const int lane = t & 63;
    const int w    = t >> 6;
    const int cnt  = cand_cnt[n];

    for (int i = t; i < D_MODEL / 4; i += 256)
        reinterpret_cast<float4*>(xr)[i] =
            reinterpret_cast<const float4*>(x + (size_t)n * D_MODEL)[i];
    for (int c = t; c < cnt; c += 256) ci[c] = cand_idx[(size_t)n * cap + c];
    __syncthreads();

    for (int c = w; c < cnt; c += 4) {
        const int idx = ci[c];
        const float4* wrow = reinterpret_cast<const float4*>(We + (size_t)idx * D_MODEL);
        const float4* xro  = reinterpret_cast<const float4*>(xr);
        float s = 0.f;
        #pragma unroll
        for (int p = 0; p < 8; ++p) {
            float4 a = xro[lane + 64 * p];
            float4 b = wrow[lane + 64 * p];
            s = fmaf(a.x, b.x, s); s = fmaf(a.y, b.y, s);
            s = fmaf(a.z, b.z, s); s = fmaf(a.w, b.w, s);
        }
        #pragma unroll
        for (int sh = 1; sh < 64; sh <<= 1) s += __shfl_xor(s, sh);
        if (lane == 0) cv[c] = s + be[idx];
    }
    __syncthreads();

    if (w == 0) {
        float pv[CAPMAX / 64];
        int   pi[CAPMAX / 64];
        #pragma unroll
        for (int qq = 0; qq < CAPMAX / 64; ++qq) {
            const int c = lane + 64 * qq;
            const bool ok = c < cnt;
            pv[qq] = ok ? cv[c] : -INFINITY;
            pi[qq] = ok ? ci[c] : 0x7fffffff;
        }
        for (int r = 0; r < KTOP; ++r) {
            float bv = pv[0]; int bi = pi[0]; int bq = 0;
            #pragma unroll
            for (int qq = 1; qq < CAPMAX / 64; ++qq)
                if (pv[qq] > bv || (pv[qq] == bv && pi[qq] < bi)) {
                    bv = pv[qq]; bi = pi[qq]; bq = qq;
                }
            float gv = bv; int gi = bi;
            #pragma unroll
            for (int s = 1; s < 64; s <<= 1) {
                float ov = __shfl_xor(gv, s);
                int   oi = __shfl_xor(gi, s);
                if (ov > gv || (ov == gv && oi < gi)) { gv = ov; gi = oi; }
            }
            if (bi == gi) pv[bq] = -INFINITY;
            if (lane == 0) {
                const bool valid = (gi != 0x7fffffff);
                const float rv = (valid && gv > 0.f) ? gv : 0.f;
                valsT[r * NROWS + n] = rv;
                idxT[r * NROWS + n]  = valid ? gi : 0;
                if (valid) features[(size_t)n * DICT + gi] = rv;
            }
        }
    }
}

// ---------------------------------------------------------------------------
// Decoder: block per d, full Wd row (128KB) in LDS, 1024 threads (16 waves/CU
// for latency hiding). vals/idx read coalesced from transposed layout.
// ---------------------------------------------------------------------------
__global__ __launch_bounds__(1024) void decoder_kernel(
    const float* __restrict__ Wd,
    const float* __restrict__ bd,
    const float* __restrict__ valsT,     // [KTOP][NROWS]
    const int*   __restrict__ idxT,      // [KTOP][NROWS]
    float* __restrict__ recon)
{
    __shared__ float wrow[DICT];         // 128 KB
    const int d = blockIdx.x;
    const int t = threadIdx.x;
    const float* src = Wd + (size_t)d * DICT;

    for (int i = t; i < DICT / 4; i += 1024)
        reinterpret_cast<float4*>(wrow)[i] =
            reinterpret_cast<const float4*>(src)[i];
    __syncthreads();

    const float b = bd[d];
    #pragma unroll
    for (int u = 0; u < NROWS / 1024; ++u) {
        const int n = t + 1024 * u;
        float a0 = 0.f, a1 = 0.f, a2 = 0.f, a3 = 0.f;
        #pragma unroll
        for (int k = 0; k < KTOP; k += 8) {
            float v0 = valsT[(k + 0) * NROWS + n];
            float v1 = valsT[(k + 1) * NROWS + n];
            float v2 = valsT[(k + 2) * NROWS + n];
            float v3 = valsT[(k + 3) * NROWS + n];
            float v4 = valsT[(k + 4) * NROWS + n];
            float v5 = valsT[(k + 5) * NROWS + n];
            float v6 = valsT[(k + 6) * NROWS + n];
            float v7 = valsT[(k + 7) * NROWS + n];
            int i0 = idxT[(k + 0) * NROWS + n];
            int i1 = idxT[(k + 1) * NROWS + n];
            int i2 = idxT[(k + 2) * NROWS + n];
            int i3 = idxT[(k + 3) * NROWS + n];
            int i4 = idxT[(k + 4) * NROWS + n];
            int i5 = idxT[(k + 5) * NROWS + n];
            int i6 = idxT[(k + 6) * NROWS + n];
            int i7 = idxT[(k + 7) * NROWS + n];
            a0 = fmaf(v0, wrow[i0], a0);
            a1 = fmaf(v1, wrow[i1], a1);
            a2 = fmaf(v2, wrow[i2], a2);
            a3 = fmaf(v3, wrow[i3], a3);
            a0 = fmaf(v4, wrow[i4], a0);
            a1 = fmaf(v5, wrow[i5], a1);
            a2 = fmaf(v6, wrow[i6], a2);
            a3 = fmaf(v7, wrow[i7], a3);
        }
        recon[(size_t)n * D_MODEL + d] = ((a0 + a1) + (a2 + a3)) + b;
    }
}

// ---------------------------------------------------------------------------
extern "C" void kernel_launch(void* const* d_in, const int* in_sizes, int n_in,
                              void* d_out, int out_size, void* d_ws, size_t ws_size,
                              hipStream_t stream)
{
    const float* x  = (const float*)d_in[0];
    const float* We = (const float*)d_in[1];
    const float* be = (const float*)d_in[2];
    const float* Wd = (const float*)d_in[3];
    const float* bd = (const float*)d_in[4];

    float* out      = (float*)d_out;
    float* recon    = out;
    float* features = out + (size_t)NROWS * D_MODEL;
    float* pre      = features + (size_t)NROWS * DICT;

    unsigned short* webf = (unsigned short*)features;
    unsigned short* xbf  = webf + (size_t)TN * KSTEPS * 4096;

    // ws layout: cand [N][cap] | cnt [N] | valsT [K][N] | idxT [K][N]
    long cap_l = (long)(ws_size / 4 - (size_t)NROWS * (1 + 2 * KTOP)) / NROWS;
    int cap = (int)(cap_l < 64 ? 64 : (cap_l > CAPMAX ? CAPMAX : cap_l));

    char* ws = (char*)d_ws;
    int*   ws_cand  = (int*)ws;
    int*   ws_cnt   = (int*)(ws + (size_t)NROWS * cap * 4);
    float* ws_valsT = (float*)(ws + (size_t)NROWS * (cap + 1) * 4);
    int*   ws_idxT  = (int*)(ws + (size_t)NROWS * (cap + 1 + KTOP) * 4);

    // 1) convert + tile + swizzle operands to bf16
    const int conv_blocks = (int)(((size_t)NROWS * KSTEPS + (size_t)DICT * KSTEPS) / 256);
    convert_tiles<<<conv_blocks, 256, 0, stream>>>(x, We, xbf, webf);

    // 2) encoder GEMM (pure bf16) -> approx pre_acts
    encoder_bf16<<<TM * TN, 256, 0, stream>>>(xbf, webf, be, pre);

    // 3) zero dense features (also wipes the bf16 staging)
    hipMemsetAsync(features, 0, (size_t)NROWS * DICT * sizeof(float), stream);

    // 4) positive-value histogram candidates
    topk_cand_hist<<<NROWS, 256, 0, stream>>>(pre, ws_cand, ws_cnt, cap);

    // 5) exact recompute + exact top-32 + scatter (transposed vals/idx out)
    recompute_select_kernel<<<NROWS, 256, 0, stream>>>(
        x, We, be, ws_cand, ws_cnt, cap, features, ws_valsT, ws_idxT);

    // 6) sparse decoder
    decoder_kernel<<<D_MODEL, 1024, 0, stream>>>(
        Wd, bd, ws_valsT, ws_idxT, recon);
}

// Round 7
// 1070.467 us; speedup vs baseline: 1.6888x; 1.1244x over previous
//
#include <hip/hip_runtime.h>
#include <cstddef>
#include <cstdint>
#include <cmath>

#define D_MODEL 2048
#define DICT    32768
#define KTOP    32
#define NROWS   2048
#define NCAND_MIN 56        // candidate margin over KTOP (guards bf16 error)
#define CAPMAX  256
#define KSTEPS  (D_MODEL / 32)      // 64
#define TM      (NROWS / 128)       // 16
#define TN      (DICT / 128)        // 256

typedef float    f32x4  __attribute__((ext_vector_type(4)));
typedef __bf16   bf16x8 __attribute__((ext_vector_type(8)));
typedef unsigned short us8 __attribute__((ext_vector_type(8)));

__device__ __forceinline__ unsigned short f2bf_rne(float f) {
    unsigned u = __builtin_bit_cast(unsigned, f);
    unsigned r = u + 0x7fffu + ((u >> 16) & 1u);
    return (unsigned short)(r >> 16);
}

__device__ __forceinline__ void gload16(const void* g, const void* s) {
    __builtin_amdgcn_global_load_lds(
        (const __attribute__((address_space(1))) unsigned int*)g,
        (__attribute__((address_space(3))) unsigned int*)s, 16, 0, 0);
}

// ---------------------------------------------------------------------------
// Convert x and We f32 -> bf16, pre-tiled [tile][kstep][128 rows][32 k] with
// XOR swizzle baked in (byte ^= (row&7)<<4 within each 8KB k-step tile).
// ---------------------------------------------------------------------------
__global__ __launch_bounds__(256) void convert_tiles(
    const float* __restrict__ x,
    const float* __restrict__ We,
    unsigned short* __restrict__ xbf,     // [TM][KSTEPS][4096] ushorts
    unsigned short* __restrict__ webf)    // [TN][KSTEPS][4096] ushorts
{
    const size_t NX = (size_t)NROWS * KSTEPS;
    size_t id = (size_t)blockIdx.x * 256 + threadIdx.x;

    const float* src;
    unsigned short* dst;
    int r;
    if (id < NX) {
        const int row = (int)(id >> 6), s = (int)(id & 63);
        src = x + (size_t)row * D_MODEL + s * 32;
        r = row & 127;
        dst = xbf + ((size_t)((row >> 7) * KSTEPS + s)) * 4096;
    } else {
        id -= NX;
        const int row = (int)(id >> 6), s = (int)(id & 63);
        src = We + (size_t)row * D_MODEL + s * 32;
        r = row & 127;
        dst = webf + ((size_t)((row >> 7) * KSTEPS + s)) * 4096;
    }

    #pragma unroll
    for (int qc = 0; qc < 4; ++qc) {
        float4 v0 = reinterpret_cast<const float4*>(src)[qc * 2];
        float4 v1 = reinterpret_cast<const float4*>(src)[qc * 2 + 1];
        us8 c;
        c[0] = f2bf_rne(v0.x); c[1] = f2bf_rne(v0.y);
        c[2] = f2bf_rne(v0.z); c[3] = f2bf_rne(v0.w);
        c[4] = f2bf_rne(v1.x); c[5] = f2bf_rne(v1.y);
        c[6] = f2bf_rne(v1.z); c[7] = f2bf_rne(v1.w);
        const int byteoff = (r * 64 + qc * 16) ^ ((r & 7) << 4);
        *reinterpret_cast<us8*>(reinterpret_cast<char*>(dst) + byteoff) = c;
    }
}

// ---------------------------------------------------------------------------
// Encoder GEMM, pure bf16. Triple-buffered LDS (depth-2 prefetch) with raw
// s_barrier + counted s_waitcnt vmcnt(8). Round-6 bug: buffer rotation
// produced index 4 (OOB) when cur==2 — fixed to true (cur+2)%3.
// ---------------------------------------------------------------------------
__global__ __launch_bounds__(256, 3) void encoder_bf16(
    const unsigned short* __restrict__ xbf,
    const unsigned short* __restrict__ webf,
    const float* __restrict__ bias,
    float* __restrict__ C)
{
    __shared__ __align__(16) unsigned short Abuf[3][4096];   // 8KB each
    __shared__ __align__(16) unsigned short Bbuf[3][4096];

    const int t    = threadIdx.x;
    const int lane = t & 63;
    const int w    = t >> 6;
    const int wr   = w >> 1;
    const int wc   = w & 1;

    const int bid = blockIdx.x;
    const int swz = (bid & 7) * (TM * TN / 8) + (bid >> 3);
    const int mt  = swz & (TM - 1);
    const int nt  = swz >> 4;

    const char* Asrc = (const char*)(xbf  + (size_t)mt * KSTEPS * 4096);
    const char* Bsrc = (const char*)(webf + (size_t)nt * KSTEPS * 4096);

    f32x4 acc[4][4];
    #pragma unroll
    for (int i = 0; i < 4; ++i)
        #pragma unroll
        for (int j = 0; j < 4; ++j) acc[i][j] = (f32x4)0.f;

    const int lchunk = w * 1024 + lane * 16;

    #define STAGE(buf, kt) do {                                              \
        const char* a_ = Asrc + (size_t)(kt) * 8192;                         \
        const char* b_ = Bsrc + (size_t)(kt) * 8192;                         \
        gload16(a_ + lchunk,        &Abuf[buf][w * 512]);                    \
        gload16(a_ + lchunk + 4096, &Abuf[buf][w * 512 + 2048]);             \
        gload16(b_ + lchunk,        &Bbuf[buf][w * 512]);                    \
        gload16(b_ + lchunk + 4096, &Bbuf[buf][w * 512 + 2048]);             \
    } while (0)

    // prologue: 2 stages in flight
    STAGE(0, 0);
    STAGE(1, 1);

    // fragment LDS offsets (loop-invariant)
    const int q16 = (lane >> 4) * 16;
    int offa[4], offb[4];
    #pragma unroll
    for (int i = 0; i < 4; ++i) {
        const int ra = wr * 64 + i * 16 + (lane & 15);
        offa[i] = ((ra * 64 + q16) ^ ((ra & 7) << 4)) >> 1;
        const int rb = wc * 64 + i * 16 + (lane & 15);
        offb[i] = ((rb * 64 + q16) ^ ((rb & 7) << 4)) >> 1;
    }

    int cur = 0;
    for (int kt = 0; kt < KSTEPS; ++kt) {
        // issue depth-2 prefetch BEFORE waiting; (cur+2)%3 buffer rotation
        if (kt + 2 < KSTEPS) STAGE((cur >= 1) ? cur - 1 : cur + 2, kt + 2);
        __builtin_amdgcn_sched_barrier(0);
        // wait only for stage kt (oldest 4 loads); 8 newer loads stay in flight
        if (kt + 2 < KSTEPS)      asm volatile("s_waitcnt vmcnt(8)" ::: "memory");
        else if (kt + 1 < KSTEPS) asm volatile("s_waitcnt vmcnt(4)" ::: "memory");
        else                      asm volatile("s_waitcnt vmcnt(0)" ::: "memory");
        __builtin_amdgcn_s_barrier();
        __builtin_amdgcn_sched_barrier(0);

        bf16x8 fa[4], fb[4];
        #pragma unroll
        for (int i = 0; i < 4; ++i)
            fa[i] = __builtin_bit_cast(bf16x8,
                *reinterpret_cast<const us8*>(&Abuf[cur][offa[i]]));
        #pragma unroll
        for (int j = 0; j < 4; ++j)
            fb[j] = __builtin_bit_cast(bf16x8,
                *reinterpret_cast<const us8*>(&Bbuf[cur][offb[j]]));
        #pragma unroll
        for (int i = 0; i < 4; ++i)
            #pragma unroll
            for (int j = 0; j < 4; ++j)
                acc[i][j] = __builtin_amdgcn_mfma_f32_16x16x32_bf16(
                    fa[i], fb[j], acc[i][j], 0, 0, 0);

        // all ds_reads complete before buffer recycled; loads NOT drained
        asm volatile("s_waitcnt lgkmcnt(0)" ::: "memory");
        __builtin_amdgcn_sched_barrier(0);
        __builtin_amdgcn_s_barrier();

        cur = (cur == 2) ? 0 : cur + 1;
    }
    #undef STAGE

    const int m0 = mt * 128, n0 = nt * 128;
    #pragma unroll
    for (int j = 0; j < 4; ++j) {
        const int col = n0 + wc * 64 + j * 16 + (lane & 15);
        const float bv = bias[col];
        #pragma unroll
        for (int i = 0; i < 4; ++i) {
            const int rowb = m0 + wr * 64 + i * 16 + ((lane >> 4) * 4);
            #pragma unroll
            for (int r = 0; r < 4; ++r)
                C[(size_t)(rowb + r) * DICT + col] = acc[i][j][r] + bv;
        }
    }
}

// ---------------------------------------------------------------------------
// Histogram radix-select of positive candidates. One block per row.
// ---------------------------------------------------------------------------
__global__ __launch_bounds__(256) void topk_cand_hist(
    const float* __restrict__ pre,
    int* __restrict__ cand_idx,
    int* __restrict__ cand_cnt,
    int cap)
{
    __shared__ unsigned hist[4096];
    __shared__ unsigned part[2][256];
    __shared__ int s_thr;
    __shared__ unsigned s_cnt;

    const int n = blockIdx.x;
    const int t = threadIdx.x;
    const float4* src = reinterpret_cast<const float4*>(pre + (size_t)n * DICT);

    for (int i = t; i < 4096; i += 256) hist[i] = 0;
    if (t == 0) { s_thr = -1; s_cnt = 0; }
    __syncthreads();

    #pragma unroll 4
    for (int p = 0; p < DICT / 1024; ++p) {
        float4 v = src[t + 256 * p];
        float e[4] = {v.x, v.y, v.z, v.w};
        #pragma unroll
        for (int j = 0; j < 4; ++j)
            if (e[j] > 0.f)
                atomicAdd(&hist[__builtin_bit_cast(unsigned, e[j]) >> 19], 1u);
    }
    __syncthreads();

    unsigned hv[16];
    unsigned local = 0;
    #pragma unroll
    for (int b = 0; b < 16; ++b) { hv[b] = hist[t * 16 + b]; local += hv[b]; }
    part[0][t] = local;
    __syncthreads();
    int sb = 0;
    for (int s = 1; s < 256; s <<= 1) {
        unsigned v2 = part[sb][t];
        if (t + s < 256) v2 += part[sb][t + s];
        part[sb ^ 1][t] = v2;
        sb ^= 1;
        __syncthreads();
    }
    const unsigned above = (t < 255) ? part[sb][t + 1] : 0;

    unsigned cum = above;
    int mybin = -1;
    #pragma unroll
    for (int b = 15; b >= 0; --b) {
        cum += hv[b];
        if (mybin < 0 && cum >= NCAND_MIN) mybin = t * 16 + b;
    }
    if (mybin >= 0) atomicMax(&s_thr, mybin);
    __syncthreads();
    const unsigned thr = (s_thr < 0) ? 0u : (unsigned)s_thr;

    for (int p = 0; p < DICT / 1024; ++p) {
        float4 v = src[t + 256 * p];
        float e[4] = {v.x, v.y, v.z, v.w};
        #pragma unroll
        for (int j = 0; j < 4; ++j) {
            if (e[j] > 0.f &&
                (__builtin_bit_cast(unsigned, e[j]) >> 19) >= thr) {
                unsigned pos = atomicAdd(&s_cnt, 1u);
                if (pos < (unsigned)cap)
                    cand_idx[(size_t)n * cap + pos] = (t + 256 * p) * 4 + j;
            }
        }
    }
    __syncthreads();
    if (t == 0) cand_cnt[n] = (int)min(s_cnt, (unsigned)cap);
}

// ---------------------------------------------------------------------------
// Exact f32 recompute + exact top-32 + relu + scatter.
// Writes vals/idx in TRANSPOSED [KTOP][NROWS] layout for coalesced decoder.
// ---------------------------------------------------------------------------
__global__ __launch_bounds__(256) void recompute_select_kernel(
    const float* __restrict__ x,
    const float* __restrict__ We,
    const float* __restrict__ be,
    const int*   __restrict__ cand_idx,
    const int*   __restrict__ cand_cnt,
    int cap,
    float* __restrict__ features,
    float* __restrict__ valsT,           // [KTOP][NROWS]
    int*   __restrict__ idxT)            // [KTOP][NROWS]
{
    __shared__ float xr[D_MODEL];
    __shared__ float cv[CAPMAX];
    __shared__ int   ci[CAPMAX];

    const int n    = blockIdx.x;
    const int t    = threadIdx.x;
    const int lane = t & 63;
    const int w    = t >> 6;
    const int cnt  = cand_cnt[n];

    for (int i = t; i < D_MODEL / 4; i += 256)
        reinterpret_cast<float4*>(xr)[i] =
            reinterpret_cast<const float4*>(x + (size_t)n * D_MODEL)[i];
    for (int c = t; c < cnt; c += 256) ci[c] = cand_idx[(size_t)n * cap + c];
    __syncthreads();

    for (int c = w; c < cnt; c += 4) {
        const int idx = ci[c];
        const float4* wrow = reinterpret_cast<const float4*>(We + (size_t)idx * D_MODEL);
        const float4* xro  = reinterpret_cast<const float4*>(xr);
        float s = 0.f;
        #pragma unroll
        for (int p = 0; p < 8; ++p) {
            float4 a = xro[lane + 64 * p];
            float4 b = wrow[lane + 64 * p];
            s = fmaf(a.x, b.x, s); s = fmaf(a.y, b.y, s);
            s = fmaf(a.z, b.z, s); s = fmaf(a.w, b.w, s);
        }
        #pragma unroll
        for (int sh = 1; sh < 64; sh <<= 1) s += __shfl_xor(s, sh);
        if (lane == 0) cv[c] = s + be[idx];
    }
    __syncthreads();

    if (w == 0) {
        float pv[CAPMAX / 64];
        int   pi[CAPMAX / 64];
        #pragma unroll
        for (int qq = 0; qq < CAPMAX / 64; ++qq) {
            const int c = lane + 64 * qq;
            const bool ok = c < cnt;
            pv[qq] = ok ? cv[c] : -INFINITY;
            pi[qq] = ok ? ci[c] : 0x7fffffff;
        }
        for (int r = 0; r < KTOP; ++r) {
            float bv = pv[0]; int bi = pi[0]; int bq = 0;
            #pragma unroll
            for (int qq = 1; qq < CAPMAX / 64; ++qq)
                if (pv[qq] > bv || (pv[qq] == bv && pi[qq] < bi)) {
                    bv = pv[qq]; bi = pi[qq]; bq = qq;
                }
            float gv = bv; int gi = bi;
            #pragma unroll
            for (int s = 1; s < 64; s <<= 1) {
                float ov = __shfl_xor(gv, s);
                int   oi = __shfl_xor(gi, s);
                if (ov > gv || (ov == gv && oi < gi)) { gv = ov; gi = oi; }
            }
            if (bi == gi) pv[bq] = -INFINITY;
            if (lane == 0) {
                const bool valid = (gi != 0x7fffffff);
                const float rv = (valid && gv > 0.f) ? gv : 0.f;
                valsT[r * NROWS + n] = rv;
                idxT[r * NROWS + n]  = valid ? gi : 0;
                if (valid) features[(size_t)n * DICT + gi] = rv;
            }
        }
    }
}

// ---------------------------------------------------------------------------
// Decoder: block per d, full Wd row (128KB) in LDS, 1024 threads.
// ---------------------------------------------------------------------------
__global__ __launch_bounds__(1024) void decoder_kernel(
    const float* __restrict__ Wd,
    const float* __restrict__ bd,
    const float* __restrict__ valsT,     // [KTOP][NROWS]
    const int*   __restrict__ idxT,      // [KTOP][NROWS]
    float* __restrict__ recon)
{
    __shared__ float wrow[DICT];         // 128 KB
    const int d = blockIdx.x;
    const int t = threadIdx.x;
    const float* src = Wd + (size_t)d * DICT;

    for (int i = t; i < DICT / 4; i += 1024)
        reinterpret_cast<float4*>(wrow)[i] =
            reinterpret_cast<const float4*>(src)[i];
    __syncthreads();

    const float b = bd[d];
    #pragma unroll
    for (int u = 0; u < NROWS / 1024; ++u) {
        const int n = t + 1024 * u;
        float a0 = 0.f, a1 = 0.f, a2 = 0.f, a3 = 0.f;
        #pragma unroll
        for (int k = 0; k < KTOP; k += 8) {
            float v0 = valsT[(k + 0) * NROWS + n];
            float v1 = valsT[(k + 1) * NROWS + n];
            float v2 = valsT[(k + 2) * NROWS + n];
            float v3 = valsT[(k + 3) * NROWS + n];
            float v4 = valsT[(k + 4) * NROWS + n];
            float v5 = valsT[(k + 5) * NROWS + n];
            float v6 = valsT[(k + 6) * NROWS + n];
            float v7 = valsT[(k + 7) * NROWS + n];
            int i0 = idxT[(k + 0) * NROWS + n];
            int i1 = idxT[(k + 1) * NROWS + n];
            int i2 = idxT[(k + 2) * NROWS + n];
            int i3 = idxT[(k + 3) * NROWS + n];
            int i4 = idxT[(k + 4) * NROWS + n];
            int i5 = idxT[(k + 5) * NROWS + n];
            int i6 = idxT[(k + 6) * NROWS + n];
            int i7 = idxT[(k + 7) * NROWS + n];
            a0 = fmaf(v0, wrow[i0], a0);
            a1 = fmaf(v1, wrow[i1], a1);
            a2 = fmaf(v2, wrow[i2], a2);
            a3 = fmaf(v3, wrow[i3], a3);
            a0 = fmaf(v4, wrow[i4], a0);
            a1 = fmaf(v5, wrow[i5], a1);
            a2 = fmaf(v6, wrow[i6], a2);
            a3 = fmaf(v7, wrow[i7], a3);
        }
        recon[(size_t)n * D_MODEL + d] = ((a0 + a1) + (a2 + a3)) + b;
    }
}

// ---------------------------------------------------------------------------
extern "C" void kernel_launch(void* const* d_in, const int* in_sizes, int n_in,
                              void* d_out, int out_size, void* d_ws, size_t ws_size,
                              hipStream_t stream)
{
    const float* x  = (const float*)d_in[0];
    const float* We = (const float*)d_in[1];
    const float* be = (const float*)d_in[2];
    const float* Wd = (const float*)d_in[3];
    const float* bd = (const float*)d_in[4];

    float* out      = (float*)d_out;
    float* recon    = out;
    float* features = out + (size_t)NROWS * D_MODEL;
    float* pre      = features + (size_t)NROWS * DICT;

    unsigned short* webf = (unsigned short*)features;
    unsigned short* xbf  = webf + (size_t)TN * KSTEPS * 4096;

    long cap_l = (long)(ws_size / 4 - (size_t)NROWS * (1 + 2 * KTOP)) / NROWS;
    int cap = (int)(cap_l < 64 ? 64 : (cap_l > CAPMAX ? CAPMAX : cap_l));

    char* ws = (char*)d_ws;
    int*   ws_cand  = (int*)ws;
    int*   ws_cnt   = (int*)(ws + (size_t)NROWS * cap * 4);
    float* ws_valsT = (float*)(ws + (size_t)NROWS * (cap + 1) * 4);
    int*   ws_idxT  = (int*)(ws + (size_t)NROWS * (cap + 1 + KTOP) * 4);

    // 1) convert + tile + swizzle operands to bf16
    const int conv_blocks = (int)(((size_t)NROWS * KSTEPS + (size_t)DICT * KSTEPS) / 256);
    convert_tiles<<<conv_blocks, 256, 0, stream>>>(x, We, xbf, webf);

    // 2) encoder GEMM (pure bf16, counted-vmcnt pipeline) -> approx pre_acts
    encoder_bf16<<<TM * TN, 256, 0, stream>>>(xbf, webf, be, pre);

    // 3) zero dense features (also wipes the bf16 staging)
    hipMemsetAsync(features, 0, (size_t)NROWS * DICT * sizeof(float), stream);

    // 4) positive-value histogram candidates
    topk_cand_hist<<<NROWS, 256, 0, stream>>>(pre, ws_cand, ws_cnt, cap);

    // 5) exact recompute + exact top-32 + scatter (transposed vals/idx out)
    recompute_select_kernel<<<NROWS, 256, 0, stream>>>(
        x, We, be, ws_cand, ws_cnt, cap, features, ws_valsT, ws_idxT);

    // 6) sparse decoder
    decoder_kernel<<<D_MODEL, 1024, 0, stream>>>(
        Wd, bd, ws_valsT, ws_idxT, recon);
}

// Round 8
// 1026.487 us; speedup vs baseline: 1.7612x; 1.0428x over previous
//
#include <hip/hip_runtime.h>
#include <cstddef>
#include <cstdint>
#include <cmath>

#define D_MODEL 2048
#define DICT    32768
#define KTOP    32
#define NROWS   2048
#define NCAND_MIN 56        // candidate margin over KTOP (guards bf16 error)
#define CAPMAX  256
#define KSTEPS  (D_MODEL / 32)      // 64 K-steps of BK=32
#define TMB     (NROWS / 256)       // 8  row tiles (256 rows)
#define TNB     (DICT / 256)        // 128 col tiles (256 cols)

typedef float    f32x4  __attribute__((ext_vector_type(4)));
typedef __bf16   bf16x8 __attribute__((ext_vector_type(8)));
typedef unsigned short us8 __attribute__((ext_vector_type(8)));

__device__ __forceinline__ unsigned short f2bf_rne(float f) {
    unsigned u = __builtin_bit_cast(unsigned, f);
    unsigned r = u + 0x7fffu + ((u >> 16) & 1u);
    return (unsigned short)(r >> 16);
}

__device__ __forceinline__ void gload16(const void* g, const void* s) {
    __builtin_amdgcn_global_load_lds(
        (const __attribute__((address_space(1))) unsigned int*)g,
        (__attribute__((address_space(3))) unsigned int*)s, 16, 0, 0);
}

// ---------------------------------------------------------------------------
// Convert x and We f32 -> bf16, pre-tiled [tile(256 rows)][kstep][256*32] with
// XOR swizzle baked in (byte ^= (row&7)<<4 within each 16KB k-step tile).
// One thread = one (row, kstep) pair = 32 elements.
// ---------------------------------------------------------------------------
__global__ __launch_bounds__(256) void convert_tiles(
    const float* __restrict__ x,
    const float* __restrict__ We,
    unsigned short* __restrict__ xbf,     // [TMB][KSTEPS][8192] ushorts
    unsigned short* __restrict__ webf)    // [TNB][KSTEPS][8192] ushorts
{
    const size_t NX = (size_t)NROWS * KSTEPS;
    size_t id = (size_t)blockIdx.x * 256 + threadIdx.x;

    const float* src;
    unsigned short* dst;
    int r;
    if (id < NX) {
        const int row = (int)(id >> 6), s = (int)(id & 63);
        src = x + (size_t)row * D_MODEL + s * 32;
        r = row & 255;
        dst = xbf + ((size_t)((row >> 8) * KSTEPS + s)) * 8192;
    } else {
        id -= NX;
        const int row = (int)(id >> 6), s = (int)(id & 63);
        src = We + (size_t)row * D_MODEL + s * 32;
        r = row & 255;
        dst = webf + ((size_t)((row >> 8) * KSTEPS + s)) * 8192;
    }

    #pragma unroll
    for (int qc = 0; qc < 4; ++qc) {
        float4 v0 = reinterpret_cast<const float4*>(src)[qc * 2];
        float4 v1 = reinterpret_cast<const float4*>(src)[qc * 2 + 1];
        us8 c;
        c[0] = f2bf_rne(v0.x); c[1] = f2bf_rne(v0.y);
        c[2] = f2bf_rne(v0.z); c[3] = f2bf_rne(v0.w);
        c[4] = f2bf_rne(v1.x); c[5] = f2bf_rne(v1.y);
        c[6] = f2bf_rne(v1.z); c[7] = f2bf_rne(v1.w);
        const int byteoff = (r * 64 + qc * 16) ^ ((r & 7) << 4);
        *reinterpret_cast<us8*>(reinterpret_cast<char*>(dst) + byteoff) = c;
    }
}

// ---------------------------------------------------------------------------
// Encoder GEMM, pure bf16. 256x256 block tile, 8 waves (2x4), wave tile
// 128x64 (8x4 16x16x32 frags -> FLOP/LDS-byte doubled vs 64x64). Triple-
// buffered LDS K-steps with r7's proven depth-2 counted-vmcnt(8) ledger.
// Two 16-MFMA clusters per K-step wrapped in s_setprio (T5 role-split).
// ---------------------------------------------------------------------------
__global__ __launch_bounds__(512, 2) void encoder_bf16(
    const unsigned short* __restrict__ xbf,
    const unsigned short* __restrict__ webf,
    const float* __restrict__ bias,
    float* __restrict__ C)
{
    __shared__ __align__(16) unsigned short Abuf[3][8192];   // 16KB each
    __shared__ __align__(16) unsigned short Bbuf[3][8192];

    const int t    = threadIdx.x;
    const int lane = t & 63;
    const int w    = t >> 6;        // 0..7
    const int wm   = w >> 2;        // 0..1  (128-row half)
    const int wn   = w & 3;         // 0..3  (64-col quarter)

    // XCD-bijective swizzle: 1024 blocks, 8 consecutive same-XCD share nt
    const int bid = blockIdx.x;
    const int swz = (bid & 7) * (TMB * TNB / 8) + (bid >> 3);
    const int mt  = swz & (TMB - 1);
    const int nt  = swz >> 3;

    const char* Asrc = (const char*)(xbf  + (size_t)mt * KSTEPS * 8192);
    const char* Bsrc = (const char*)(webf + (size_t)nt * KSTEPS * 8192);

    f32x4 acc[8][4];
    #pragma unroll
    for (int i = 0; i < 8; ++i)
        #pragma unroll
        for (int j = 0; j < 4; ++j) acc[i][j] = (f32x4)0.f;

    const int lb = t * 16;   // this thread's byte chunk (0..8191)

    #define STAGE(buf, kt) do {                                              \
        const char* a_ = Asrc + (size_t)(kt) * 16384;                        \
        const char* b_ = Bsrc + (size_t)(kt) * 16384;                        \
        gload16(a_ + lb,        &Abuf[buf][t * 8]);                          \
        gload16(a_ + lb + 8192, &Abuf[buf][t * 8 + 4096]);                   \
        gload16(b_ + lb,        &Bbuf[buf][t * 8]);                          \
        gload16(b_ + lb + 8192, &Bbuf[buf][t * 8 + 4096]);                   \
    } while (0)

    // prologue: 2 stages in flight (r7 ledger)
    STAGE(0, 0);
    STAGE(1, 1);

    // fragment LDS offsets (loop-invariant), ushort units
    const int q16 = (lane >> 4) * 16;
    int offa[8], offb[4];
    #pragma unroll
    for (int i = 0; i < 8; ++i) {
        const int ra = wm * 128 + i * 16 + (lane & 15);
        offa[i] = ((ra * 64 + q16) ^ ((ra & 7) << 4)) >> 1;
    }
    #pragma unroll
    for (int j = 0; j < 4; ++j) {
        const int rb = wn * 64 + j * 16 + (lane & 15);
        offb[j] = ((rb * 64 + q16) ^ ((rb & 7) << 4)) >> 1;
    }

    int cur = 0;
    for (int kt = 0; kt < KSTEPS; ++kt) {
        // depth-2 prefetch, (cur+2)%3 rotation (r7-proven)
        if (kt + 2 < KSTEPS) STAGE((cur >= 1) ? cur - 1 : cur + 2, kt + 2);
        __builtin_amdgcn_sched_barrier(0);
        // wait only for stage kt; 8 newer loads stay in flight across barriers
        if (kt + 2 < KSTEPS)      asm volatile("s_waitcnt vmcnt(8)" ::: "memory");
        else if (kt + 1 < KSTEPS) asm volatile("s_waitcnt vmcnt(4)" ::: "memory");
        else                      asm volatile("s_waitcnt vmcnt(0)" ::: "memory");
        __builtin_amdgcn_s_barrier();
        __builtin_amdgcn_sched_barrier(0);

        // phase A: B frags + first 4 A frags -> 16 MFMA
        bf16x8 fb[4], fa[4];
        #pragma unroll
        for (int j = 0; j < 4; ++j)
            fb[j] = __builtin_bit_cast(bf16x8,
                *reinterpret_cast<const us8*>(&Bbuf[cur][offb[j]]));
        #pragma unroll
        for (int i = 0; i < 4; ++i)
            fa[i] = __builtin_bit_cast(bf16x8,
                *reinterpret_cast<const us8*>(&Abuf[cur][offa[i]]));
        __builtin_amdgcn_s_setprio(1);
        #pragma unroll
        for (int i = 0; i < 4; ++i)
            #pragma unroll
            for (int j = 0; j < 4; ++j)
                acc[i][j] = __builtin_amdgcn_mfma_f32_16x16x32_bf16(
                    fa[i], fb[j], acc[i][j], 0, 0, 0);
        __builtin_amdgcn_s_setprio(0);

        // phase B: last 4 A frags -> 16 MFMA
        bf16x8 fa2[4];
        #pragma unroll
        for (int i = 0; i < 4; ++i)
            fa2[i] = __builtin_bit_cast(bf16x8,
                *reinterpret_cast<const us8*>(&Abuf[cur][offa[i + 4]]));
        __builtin_amdgcn_s_setprio(1);
        #pragma unroll
        for (int i = 0; i < 4; ++i)
            #pragma unroll
            for (int j = 0; j < 4; ++j)
                acc[i + 4][j] = __builtin_amdgcn_mfma_f32_16x16x32_bf16(
                    fa2[i], fb[j], acc[i + 4][j], 0, 0, 0);
        __builtin_amdgcn_s_setprio(0);

        // buffer-recycle fence: ds_reads done before next stage overwrites
        asm volatile("s_waitcnt lgkmcnt(0)" ::: "memory");
        __builtin_amdgcn_sched_barrier(0);
        __builtin_amdgcn_s_barrier();

        cur = (cur == 2) ? 0 : cur + 1;
    }
    #undef STAGE

    const int m0 = mt * 256, n0 = nt * 256;
    #pragma unroll
    for (int j = 0; j < 4; ++j) {
        const int col = n0 + wn * 64 + j * 16 + (lane & 15);
        const float bv = bias[col];
        #pragma unroll
        for (int i = 0; i < 8; ++i) {
            const int rowb = m0 + wm * 128 + i * 16 + ((lane >> 4) * 4);
            #pragma unroll
            for (int r = 0; r < 4; ++r)
                C[(size_t)(rowb + r) * DICT + col] = acc[i][j][r] + bv;
        }
    }
}

// ---------------------------------------------------------------------------
// Histogram radix-select of positive candidates. One block per row.
// ---------------------------------------------------------------------------
__global__ __launch_bounds__(256) void topk_cand_hist(
    const float* __restrict__ pre,
    int* __restrict__ cand_idx,
    int* __restrict__ cand_cnt,
    int cap)
{
    __shared__ unsigned hist[4096];
    __shared__ unsigned part[2][256];
    __shared__ int s_thr;
    __shared__ unsigned s_cnt;

    const int n = blockIdx.x;
    const int t = threadIdx.x;
    const float4* src = reinterpret_cast<const float4*>(pre + (size_t)n * DICT);

    for (int i = t; i < 4096; i += 256) hist[i] = 0;
    if (t == 0) { s_thr = -1; s_cnt = 0; }
    __syncthreads();

    #pragma unroll 4
    for (int p = 0; p < DICT / 1024; ++p) {
        float4 v = src[t + 256 * p];
        float e[4] = {v.x, v.y, v.z, v.w};
        #pragma unroll
        for (int j = 0; j < 4; ++j)
            if (e[j] > 0.f)
                atomicAdd(&hist[__builtin_bit_cast(unsigned, e[j]) >> 19], 1u);
    }
    __syncthreads();

    unsigned hv[16];
    unsigned local = 0;
    #pragma unroll
    for (int b = 0; b < 16; ++b) { hv[b] = hist[t * 16 + b]; local += hv[b]; }
    part[0][t] = local;
    __syncthreads();
    int sb = 0;
    for (int s = 1; s < 256; s <<= 1) {
        unsigned v2 = part[sb][t];
        if (t + s < 256) v2 += part[sb][t + s];
        part[sb ^ 1][t] = v2;
        sb ^= 1;
        __syncthreads();
    }
    const unsigned above = (t < 255) ? part[sb][t + 1] : 0;

    unsigned cum = above;
    int mybin = -1;
    #pragma unroll
    for (int b = 15; b >= 0; --b) {
        cum += hv[b];
        if (mybin < 0 && cum >= NCAND_MIN) mybin = t * 16 + b;
    }
    if (mybin >= 0) atomicMax(&s_thr, mybin);
    __syncthreads();
    const unsigned thr = (s_thr < 0) ? 0u : (unsigned)s_thr;

    for (int p = 0; p < DICT / 1024; ++p) {
        float4 v = src[t + 256 * p];
        float e[4] = {v.x, v.y, v.z, v.w};
        #pragma unroll
        for (int j = 0; j < 4; ++j) {
            if (e[j] > 0.f &&
                (__builtin_bit_cast(unsigned, e[j]) >> 19) >= thr) {
                unsigned pos = atomicAdd(&s_cnt, 1u);
                if (pos < (unsigned)cap)
                    cand_idx[(size_t)n * cap + pos] = (t + 256 * p) * 4 + j;
            }
        }
    }
    __syncthreads();
    if (t == 0) cand_cnt[n] = (int)min(s_cnt, (unsigned)cap);
}

// ---------------------------------------------------------------------------
// Exact f32 recompute + exact top-32 + relu + scatter.
// Writes vals/idx in TRANSPOSED [KTOP][NROWS] layout for coalesced decoder.
// ---------------------------------------------------------------------------
__global__ __launch_bounds__(256) void recompute_select_kernel(
    const float* __restrict__ x,
    const float* __restrict__ We,
    const float* __restrict__ be,
    const int*   __restrict__ cand_idx,
    const int*   __restrict__ cand_cnt,
    int cap,
    float* __restrict__ features,
    float* __restrict__ valsT,           // [KTOP][NROWS]
    int*   __restrict__ idxT)            // [KTOP][NROWS]
{
    __shared__ float xr[D_MODEL];
    __shared__ float cv[CAPMAX];
    __shared__ int   ci[CAPMAX];

    const int n    = blockIdx.x;
    const int t    = threadIdx.x;
    const int lane = t & 63;
    const int w    = t >> 6;
    const int cnt  = cand_cnt[n];

    for (int i = t; i < D_MODEL / 4; i += 256)
        reinterpret_cast<float4*>(xr)[i] =
            reinterpret_cast<const float4*>(x + (size_t)n * D_MODEL)[i];
    for (int c = t; c < cnt; c += 256) ci[c] = cand_idx[(size_t)n * cap + c];
    __syncthreads();

    for (int c = w; c < cnt; c += 4) {
        const int idx = ci[c];
        const float4* wrow = reinterpret_cast<const float4*>(We + (size_t)idx * D_MODEL);
        const float4* xro  = reinterpret_cast<const float4*>(xr);
        float s = 0.f;
        #pragma unroll
        for (int p = 0; p < 8; ++p) {
            float4 a = xro[lane + 64 * p];
            float4 b = wrow[lane + 64 * p];
            s = fmaf(a.x, b.x, s); s = fmaf(a.y, b.y, s);
            s = fmaf(a.z, b.z, s); s = fmaf(a.w, b.w, s);
        }
        #pragma unroll
        for (int sh = 1; sh < 64; sh <<= 1) s += __shfl_xor(s, sh);
        if (lane == 0) cv[c] = s + be[idx];
    }
    __syncthreads();

    if (w == 0) {
        float pv[CAPMAX / 64];
        int   pi[CAPMAX / 64];
        #pragma unroll
        for (int qq = 0; qq < CAPMAX / 64; ++qq) {
            const int c = lane + 64 * qq;
            const bool ok = c < cnt;
            pv[qq] = ok ? cv[c] : -INFINITY;
            pi[qq] = ok ? ci[c] : 0x7fffffff;
        }
        for (int r = 0; r < KTOP; ++r) {
            float bv = pv[0]; int bi = pi[0]; int bq = 0;
            #pragma unroll
            for (int qq = 1; qq < CAPMAX / 64; ++qq)
                if (pv[qq] > bv || (pv[qq] == bv && pi[qq] < bi)) {
                    bv = pv[qq]; bi = pi[qq]; bq = qq;
                }
            float gv = bv; int gi = bi;
            #pragma unroll
            for (int s = 1; s < 64; s <<= 1) {
                float ov = __shfl_xor(gv, s);
                int   oi = __shfl_xor(gi, s);
                if (ov > gv || (ov == gv && oi < gi)) { gv = ov; gi = oi; }
            }
            if (bi == gi) pv[bq] = -INFINITY;
            if (lane == 0) {
                const bool valid = (gi != 0x7fffffff);
                const float rv = (valid && gv > 0.f) ? gv : 0.f;
                valsT[r * NROWS + n] = rv;
                idxT[r * NROWS + n]  = valid ? gi : 0;
                if (valid) features[(size_t)n * DICT + gi] = rv;
            }
        }
    }
}

// ---------------------------------------------------------------------------
// Decoder: block per d, full Wd row (128KB) in LDS, 1024 threads.
// ---------------------------------------------------------------------------
__global__ __launch_bounds__(1024) void decoder_kernel(
    const float* __restrict__ Wd,
    const float* __restrict__ bd,
    const float* __restrict__ valsT,     // [KTOP][NROWS]
    const int*   __restrict__ idxT,      // [KTOP][NROWS]
    float* __restrict__ recon)
{
    __shared__ float wrow[DICT];         // 128 KB
    const int d = blockIdx.x;
    const int t = threadIdx.x;
    const float* src = Wd + (size_t)d * DICT;

    for (int i = t; i < DICT / 4; i += 1024)
        reinterpret_cast<float4*>(wrow)[i] =
            reinterpret_cast<const float4*>(src)[i];
    __syncthreads();

    const float b = bd[d];
    #pragma unroll
    for (int u = 0; u < NROWS / 1024; ++u) {
        const int n = t + 1024 * u;
        float a0 = 0.f, a1 = 0.f, a2 = 0.f, a3 = 0.f;
        #pragma unroll
        for (int k = 0; k < KTOP; k += 8) {
            float v0 = valsT[(k + 0) * NROWS + n];
            float v1 = valsT[(k + 1) * NROWS + n];
            float v2 = valsT[(k + 2) * NROWS + n];
            float v3 = valsT[(k + 3) * NROWS + n];
            float v4 = valsT[(k + 4) * NROWS + n];
            float v5 = valsT[(k + 5) * NROWS + n];
            float v6 = valsT[(k + 6) * NROWS + n];
            float v7 = valsT[(k + 7) * NROWS + n];
            int i0 = idxT[(k + 0) * NROWS + n];
            int i1 = idxT[(k + 1) * NROWS + n];
            int i2 = idxT[(k + 2) * NROWS + n];
            int i3 = idxT[(k + 3) * NROWS + n];
            int i4 = idxT[(k + 4) * NROWS + n];
            int i5 = idxT[(k + 5) * NROWS + n];
            int i6 = idxT[(k + 6) * NROWS + n];
            int i7 = idxT[(k + 7) * NROWS + n];
            a0 = fmaf(v0, wrow[i0], a0);
            a1 = fmaf(v1, wrow[i1], a1);
            a2 = fmaf(v2, wrow[i2], a2);
            a3 = fmaf(v3, wrow[i3], a3);
            a0 = fmaf(v4, wrow[i4], a0);
            a1 = fmaf(v5, wrow[i5], a1);
            a2 = fmaf(v6, wrow[i6], a2);
            a3 = fmaf(v7, wrow[i7], a3);
        }
        recon[(size_t)n * D_MODEL + d] = ((a0 + a1) + (a2 + a3)) + b;
    }
}

// ---------------------------------------------------------------------------
extern "C" void kernel_launch(void* const* d_in, const int* in_sizes, int n_in,
                              void* d_out, int out_size, void* d_ws, size_t ws_size,
                              hipStream_t stream)
{
    const float* x  = (const float*)d_in[0];
    const float* We = (const float*)d_in[1];
    const float* be = (const float*)d_in[2];
    const float* Wd = (const float*)d_in[3];
    const float* bd = (const float*)d_in[4];

    float* out      = (float*)d_out;
    float* recon    = out;
    float* features = out + (size_t)NROWS * D_MODEL;
    float* pre      = features + (size_t)NROWS * DICT;

    // bf16 tiled operands parked in the features region (memset'd after GEMM)
    unsigned short* webf = (unsigned short*)features;                 // 128 MB
    unsigned short* xbf  = webf + (size_t)TNB * KSTEPS * 8192;        // + 8 MB

    long cap_l = (long)(ws_size / 4 - (size_t)NROWS * (1 + 2 * KTOP)) / NROWS;
    int cap = (int)(cap_l < 64 ? 64 : (cap_l > CAPMAX ? CAPMAX : cap_l));

    char* ws = (char*)d_ws;
    int*   ws_cand  = (int*)ws;
    int*   ws_cnt   = (int*)(ws + (size_t)NROWS * cap * 4);
    float* ws_valsT = (float*)(ws + (size_t)NROWS * (cap + 1) * 4);
    int*   ws_idxT  = (int*)(ws + (size_t)NROWS * (cap + 1 + KTOP) * 4);

    // 1) convert + tile + swizzle operands to bf16 (256-row tiles)
    const int conv_blocks = (int)(((size_t)NROWS * KSTEPS + (size_t)DICT * KSTEPS) / 256);
    convert_tiles<<<conv_blocks, 256, 0, stream>>>(x, We, xbf, webf);

    // 2) encoder GEMM (256x256 tile, 8 waves, counted-vmcnt + setprio phases)
    encoder_bf16<<<TMB * TNB, 512, 0, stream>>>(xbf, webf, be, pre);

    // 3) zero dense features (also wipes the bf16 staging)
    hipMemsetAsync(features, 0, (size_t)NROWS * DICT * sizeof(float), stream);

    // 4) positive-value histogram candidates
    topk_cand_hist<<<NROWS, 256, 0, stream>>>(pre, ws_cand, ws_cnt, cap);

    // 5) exact recompute + exact top-32 + scatter (transposed vals/idx out)
    recompute_select_kernel<<<NROWS, 256, 0, stream>>>(
        x, We, be, ws_cand, ws_cnt, cap, features, ws_valsT, ws_idxT);

    // 6) sparse decoder
    decoder_kernel<<<D_MODEL, 1024, 0, stream>>>(
        Wd, bd, ws_valsT, ws_idxT, recon);
}

// Round 9
// 982.814 us; speedup vs baseline: 1.8395x; 1.0444x over previous
//
#include <hip/hip_runtime.h>
#include <cstddef>
#include <cstdint>
#include <cmath>

#define D_MODEL 2048
#define DICT    32768
#define KTOP    32
#define NROWS   2048
#define NCAND_MIN 56        // candidate margin over KTOP (guards bf16 error)
#define CAPMAX  256
#define BKT     64                  // K-tile depth
#define NT_K    (D_MODEL / BKT)     // 32 K-tiles
#define TMB     (NROWS / 256)       // 8  row tiles
#define TNB     (DICT / 256)        // 128 col tiles

typedef float    f32x4  __attribute__((ext_vector_type(4)));
typedef __bf16   bf16x8 __attribute__((ext_vector_type(8)));
typedef unsigned short us8 __attribute__((ext_vector_type(8)));

__device__ __forceinline__ unsigned short f2bf_rne(float f) {
    unsigned u = __builtin_bit_cast(unsigned, f);
    unsigned r = u + 0x7fffu + ((u >> 16) & 1u);
    return (unsigned short)(r >> 16);
}

__device__ __forceinline__ void gload16(const void* g, const void* s) {
    __builtin_amdgcn_global_load_lds(
        (const __attribute__((address_space(1))) unsigned int*)g,
        (__attribute__((address_space(3))) unsigned int*)s, 16, 0, 0);
}

// ---------------------------------------------------------------------------
// Convert x and We f32 -> bf16, pre-tiled per 256-row tile into 32 K-tiles of
// 64 k. Each K-tile block = [half0(rows0-127) 16KB][half1 16KB]; within a
// half, row rloc's 128B line is chunk-permuted by byte ^= ((rloc&7)<<4) —
// the inverse of the GEMM's ds_read swizzle (gload_lds dest stays linear).
// One thread = one (row, 32-k chunk) = 32 elems (128B read, 64B write).
// ---------------------------------------------------------------------------
__global__ __launch_bounds__(256) void convert_tiles(
    const float* __restrict__ x,
    const float* __restrict__ We,
    unsigned short* __restrict__ xbf,     // [TMB][NT_K][16384] ushorts
    unsigned short* __restrict__ webf)    // [TNB][NT_K][16384] ushorts
{
    const size_t NX = (size_t)NROWS * 64;
    size_t id = (size_t)blockIdx.x * 256 + threadIdx.x;

    const float* src;
    unsigned short* dstb;
    int row, s;
    if (id < NX) {
        row = (int)(id >> 6); s = (int)(id & 63);
        src = x + (size_t)row * D_MODEL + s * 32;
        dstb = xbf + ((size_t)(row >> 8) * NT_K + (s >> 1)) * 16384
                   + ((row >> 7) & 1) * 8192;
    } else {
        id -= NX;
        row = (int)(id >> 6); s = (int)(id & 63);
        src = We + (size_t)row * D_MODEL + s * 32;
        dstb = webf + ((size_t)(row >> 8) * NT_K + (s >> 1)) * 16384
                    + ((row >> 7) & 1) * 8192;
    }
    const int rloc = row & 127;
    const int koff = (s & 1) * 64;

    #pragma unroll
    for (int qc = 0; qc < 4; ++qc) {
        float4 v0 = reinterpret_cast<const float4*>(src)[qc * 2];
        float4 v1 = reinterpret_cast<const float4*>(src)[qc * 2 + 1];
        us8 c;
        c[0] = f2bf_rne(v0.x); c[1] = f2bf_rne(v0.y);
        c[2] = f2bf_rne(v0.z); c[3] = f2bf_rne(v0.w);
        c[4] = f2bf_rne(v1.x); c[5] = f2bf_rne(v1.y);
        c[6] = f2bf_rne(v1.z); c[7] = f2bf_rne(v1.w);
        const int byteoff = (rloc * 128 + koff + qc * 16) ^ ((rloc & 7) << 4);
        *reinterpret_cast<us8*>(reinterpret_cast<char*>(dstb) + byteoff) = c;
    }
}

// ---------------------------------------------------------------------------
// Encoder GEMM, pure bf16 — 8-phase schedule (m201 template, plain HIP):
// 256x256 tile, BK=64, 8 waves (2Mx4N), wave tile 128x64, LDS 128KB
// (2 dbuf x 2 half x {A,B} x 16KB). Per K-tile: 4 phases, each
// {ds-read subtile || stage 1 half-tile -> barrier -> lgkmcnt(0) ->
//  setprio(1) -> 16 MFMA -> setprio(0) -> barrier}; single counted
// vmcnt(4) per K-tile at P4 (2 half-tiles stay in flight across barriers).
// ---------------------------------------------------------------------------
__global__ __launch_bounds__(512, 2) void encoder_bf16(
    const unsigned short* __restrict__ xbf,
    const unsigned short* __restrict__ webf,
    const float* __restrict__ bias,
    float* __restrict__ C)
{
    __shared__ __align__(16) unsigned short Ab[2][2][8192];   // [dbuf][half]
    __shared__ __align__(16) unsigned short Bb[2][2][8192];

    const int t    = threadIdx.x;
    const int lane = t & 63;
    const int w    = t >> 6;        // 0..7
    const int wm   = w >> 2;        // 0..1  (128-row half; = A half index)
    const int wn   = w & 3;         // 0..3  (64-col slice)
    const int hB   = wn >> 1;       // B half index

    // XCD-bijective swizzle; 8 consecutive same-XCD blocks share nt (B panel)
    const int bid = blockIdx.x;
    const int swz = (bid & 7) * (TMB * TNB / 8) + (bid >> 3);
    const int mt  = swz & (TMB - 1);
    const int nt  = swz >> 3;

    const char* As = (const char*)xbf  + (size_t)mt * (NT_K * 32768);
    const char* Bs = (const char*)webf + (size_t)nt * (NT_K * 32768);

    f32x4 acc[8][4];
    #pragma unroll
    for (int i = 0; i < 8; ++i)
        #pragma unroll
        for (int j = 0; j < 4; ++j) acc[i][j] = (f32x4)0.f;

    const int soff = w * 2048 + lane * 16;   // byte offset in half-tile block
    const int dsti = w * 1024 + lane * 8;    // ushort idx in LDS half-buf

    #define STAGE_A(buf, u, h) do {                                          \
        const char* s_ = As + (size_t)(u) * 32768 + (h) * 16384 + soff;      \
        gload16(s_,        &Ab[buf][h][dsti]);                               \
        gload16(s_ + 1024, &Ab[buf][h][dsti + 512]);                         \
    } while (0)
    #define STAGE_B(buf, u, h) do {                                          \
        const char* s_ = Bs + (size_t)(u) * 32768 + (h) * 16384 + soff;      \
        gload16(s_,        &Bb[buf][h][dsti]);                               \
        gload16(s_ + 1024, &Bb[buf][h][dsti + 512]);                         \
    } while (0)

    bf16x8 a[4][2], b0[2][2], b1[2][2];

    #define LDA(sub) do {                                                    \
        _Pragma("unroll") for (int i = 0; i < 4; ++i)                        \
        _Pragma("unroll") for (int ks = 0; ks < 2; ++ks) {                   \
            const int rl = (sub) * 64 + i * 16 + (lane & 15);                \
            const int by = (rl * 128 + ks * 64 + ((lane >> 4) * 16))         \
                           ^ ((rl & 7) << 4);                                \
            a[i][ks] = __builtin_bit_cast(bf16x8,                            \
                *reinterpret_cast<const us8*>(                               \
                    (const char*)&Ab[cur][wm][0] + by));                     \
        } } while (0)
    #define LDB(breg, q) do {                                                \
        _Pragma("unroll") for (int j = 0; j < 2; ++j)                        \
        _Pragma("unroll") for (int ks = 0; ks < 2; ++ks) {                   \
            const int cl = (wn & 1) * 64 + (q) * 32 + j * 16 + (lane & 15);  \
            const int by = (cl * 128 + ks * 64 + ((lane >> 4) * 16))         \
                           ^ ((cl & 7) << 4);                                \
            breg[j][ks] = __builtin_bit_cast(bf16x8,                         \
                *reinterpret_cast<const us8*>(                               \
                    (const char*)&Bb[cur][hB][0] + by));                     \
        } } while (0)
    #define MMA16(ib, jb, breg) do {                                         \
        _Pragma("unroll") for (int i = 0; i < 4; ++i)                        \
        _Pragma("unroll") for (int j = 0; j < 2; ++j)                        \
        _Pragma("unroll") for (int ks = 0; ks < 2; ++ks)                     \
            acc[(ib) + i][(jb) + j] = __builtin_amdgcn_mfma_f32_16x16x32_bf16( \
                a[i][ks], breg[j][ks], acc[(ib) + i][(jb) + j], 0, 0, 0);    \
    } while (0)

    // prologue: K0 fully + K1's B halves -> 12 loads; retire through K0.
    STAGE_B(0, 0, 0); STAGE_B(0, 0, 1);
    STAGE_A(0, 0, 0); STAGE_A(0, 0, 1);
    STAGE_B(1, 1, 0); STAGE_B(1, 1, 1);
    asm volatile("s_waitcnt vmcnt(4)" ::: "memory");
    __builtin_amdgcn_sched_barrier(0);
    __builtin_amdgcn_s_barrier();

    int cur = 0;
    for (int u = 0; u < NT_K; ++u) {
        const int nxt = cur ^ 1;

        // ---- P1: ld A-sub0 (8) + B-q0 (4) || stage A0(u+1)
        LDA(0);
        LDB(b0, 0);
        if (u + 1 < NT_K) STAGE_A(nxt, u + 1, 0);
        __builtin_amdgcn_s_barrier();
        asm volatile("s_waitcnt lgkmcnt(0)" ::: "memory");
        __builtin_amdgcn_sched_barrier(0);
        __builtin_amdgcn_s_setprio(1);
        MMA16(0, 0, b0);
        __builtin_amdgcn_s_setprio(0);
        __builtin_amdgcn_s_barrier();

        // ---- P2: ld B-q1 (4) || stage A1(u+1)
        LDB(b1, 1);
        if (u + 1 < NT_K) STAGE_A(nxt, u + 1, 1);
        __builtin_amdgcn_s_barrier();
        asm volatile("s_waitcnt lgkmcnt(0)" ::: "memory");
        __builtin_amdgcn_sched_barrier(0);
        __builtin_amdgcn_s_setprio(1);
        MMA16(0, 2, b1);
        __builtin_amdgcn_s_setprio(0);
        __builtin_amdgcn_s_barrier();

        // ---- P3: ld A-sub1 (8) || stage B0(u+2)
        LDA(1);
        if (u + 2 < NT_K) STAGE_B(cur, u + 2, 0);
        __builtin_amdgcn_s_barrier();
        asm volatile("s_waitcnt lgkmcnt(0)" ::: "memory");
        __builtin_amdgcn_sched_barrier(0);
        __builtin_amdgcn_s_setprio(1);
        MMA16(4, 2, b1);
        __builtin_amdgcn_s_setprio(0);
        __builtin_amdgcn_s_barrier();

        // ---- P4: stage B1(u+2) + counted vmcnt (never 0 in steady state)
        if (u + 2 < NT_K) {
            STAGE_B(cur, u + 2, 1);
            asm volatile("s_waitcnt vmcnt(4)" ::: "memory");
        } else {
            asm volatile("s_waitcnt vmcnt(0)" ::: "memory");
        }
        __builtin_amdgcn_sched_barrier(0);
        __builtin_amdgcn_s_barrier();
        __builtin_amdgcn_s_setprio(1);
        MMA16(4, 0, b0);
        __builtin_amdgcn_s_setprio(0);
        __builtin_amdgcn_s_barrier();

        cur ^= 1;
    }
    #undef STAGE_A
    #undef STAGE_B
    #undef LDA
    #undef LDB
    #undef MMA16

    const int m0 = mt * 256, n0 = nt * 256;
    #pragma unroll
    for (int j = 0; j < 4; ++j) {
        const int col = n0 + wn * 64 + j * 16 + (lane & 15);
        const float bv = bias[col];
        #pragma unroll
        for (int i = 0; i < 8; ++i) {
            const int rowb = m0 + wm * 128 + i * 16 + ((lane >> 4) * 4);
            #pragma unroll
            for (int r = 0; r < 4; ++r)
                C[(size_t)(rowb + r) * DICT + col] = acc[i][j][r] + bv;
        }
    }
}

// ---------------------------------------------------------------------------
// Histogram radix-select of positive candidates. One block per row.
// ---------------------------------------------------------------------------
__global__ __launch_bounds__(256) void topk_cand_hist(
    const float* __restrict__ pre,
    int* __restrict__ cand_idx,
    int* __restrict__ cand_cnt,
    int cap)
{
    __shared__ unsigned hist[4096];
    __shared__ unsigned part[2][256];
    __shared__ int s_thr;
    __shared__ unsigned s_cnt;

    const int n = blockIdx.x;
    const int t = threadIdx.x;
    const float4* src = reinterpret_cast<const float4*>(pre + (size_t)n * DICT);

    for (int i = t; i < 4096; i += 256) hist[i] = 0;
    if (t == 0) { s_thr = -1; s_cnt = 0; }
    __syncthreads();

    #pragma unroll 4
    for (int p = 0; p < DICT / 1024; ++p) {
        float4 v = src[t + 256 * p];
        float e[4] = {v.x, v.y, v.z, v.w};
        #pragma unroll
        for (int j = 0; j < 4; ++j)
            if (e[j] > 0.f)
                atomicAdd(&hist[__builtin_bit_cast(unsigned, e[j]) >> 19], 1u);
    }
    __syncthreads();

    unsigned hv[16];
    unsigned local = 0;
    #pragma unroll
    for (int b = 0; b < 16; ++b) { hv[b] = hist[t * 16 + b]; local += hv[b]; }
    part[0][t] = local;
    __syncthreads();
    int sb = 0;
    for (int s = 1; s < 256; s <<= 1) {
        unsigned v2 = part[sb][t];
        if (t + s < 256) v2 += part[sb][t + s];
        part[sb ^ 1][t] = v2;
        sb ^= 1;
        __syncthreads();
    }
    const unsigned above = (t < 255) ? part[sb][t + 1] : 0;

    unsigned cum = above;
    int mybin = -1;
    #pragma unroll
    for (int b = 15; b >= 0; --b) {
        cum += hv[b];
        if (mybin < 0 && cum >= NCAND_MIN) mybin = t * 16 + b;
    }
    if (mybin >= 0) atomicMax(&s_thr, mybin);
    __syncthreads();
    const unsigned thr = (s_thr < 0) ? 0u : (unsigned)s_thr;

    for (int p = 0; p < DICT / 1024; ++p) {
        float4 v = src[t + 256 * p];
        float e[4] = {v.x, v.y, v.z, v.w};
        #pragma unroll
        for (int j = 0; j < 4; ++j) {
            if (e[j] > 0.f &&
                (__builtin_bit_cast(unsigned, e[j]) >> 19) >= thr) {
                unsigned pos = atomicAdd(&s_cnt, 1u);
                if (pos < (unsigned)cap)
                    cand_idx[(size_t)n * cap + pos] = (t + 256 * p) * 4 + j;
            }
        }
    }
    __syncthreads();
    if (t == 0) cand_cnt[n] = (int)min(s_cnt, (unsigned)cap);
}

// ---------------------------------------------------------------------------
// Exact f32 recompute + exact top-32 + relu + scatter.
// Writes vals/idx in TRANSPOSED [KTOP][NROWS] layout for coalesced decoder.
// ---------------------------------------------------------------------------
__global__ __launch_bounds__(256) void recompute_select_kernel(
    const float* __restrict__ x,
    const float* __restrict__ We,
    const float* __restrict__ be,
    const int*   __restrict__ cand_idx,
    const int*   __restrict__ cand_cnt,
    int cap,
    float* __restrict__ features,
    float* __restrict__ valsT,           // [KTOP][NROWS]
    int*   __restrict__ idxT)            // [KTOP][NROWS]
{
    __shared__ float xr[D_MODEL];
    __shared__ float cv[CAPMAX];
    __shared__ int   ci[CAPMAX];

    const int n    = blockIdx.x;
    const int t    = threadIdx.x;
    const int lane = t & 63;
    const int w    = t >> 6;
    const int cnt  = cand_cnt[n];

    for (int i = t; i < D_MODEL / 4; i += 256)
        reinterpret_cast<float4*>(xr)[i] =
            reinterpret_cast<const float4*>(x + (size_t)n * D_MODEL)[i];
    for (int c = t; c < cnt; c += 256) ci[c] = cand_idx[(size_t)n * cap + c];
    __syncthreads();

    for (int c = w; c < cnt; c += 4) {
        const int idx = ci[c];
        const float4* wrow = reinterpret_cast<const float4*>(We + (size_t)idx * D_MODEL);
        const float4* xro  = reinterpret_cast<const float4*>(xr);
        float s = 0.f;
        #pragma unroll
        for (int p = 0; p < 8; ++p) {
            float4 a = xro[lane + 64 * p];
            float4 b = wrow[lane + 64 * p];
            s = fmaf(a.x, b.x, s); s = fmaf(a.y, b.y, s);
            s = fmaf(a.z, b.z, s); s = fmaf(a.w, b.w, s);
        }
        #pragma unroll
        for (int sh = 1; sh < 64; sh <<= 1) s += __shfl_xor(s, sh);
        if (lane == 0) cv[c] = s + be[idx];
    }
    __syncthreads();

    if (w == 0) {
        float pv[CAPMAX / 64];
        int   pi[CAPMAX / 64];
        #pragma unroll
        for (int qq = 0; qq < CAPMAX / 64; ++qq) {
            const int c = lane + 64 * qq;
            const bool ok = c < cnt;
            pv[qq] = ok ? cv[c] : -INFINITY;
            pi[qq] = ok ? ci[c] : 0x7fffffff;
        }
        for (int r = 0; r < KTOP; ++r) {
            float bv = pv[0]; int bi = pi[0]; int bq = 0;
            #pragma unroll
            for (int qq = 1; qq < CAPMAX / 64; ++qq)
                if (pv[qq] > bv || (pv[qq] == bv && pi[qq] < bi)) {
                    bv = pv[qq]; bi = pi[qq]; bq = qq;
                }
            float gv = bv; int gi = bi;
            #pragma unroll
            for (int s = 1; s < 64; s <<= 1) {
                float ov = __shfl_xor(gv, s);
                int   oi = __shfl_xor(gi, s);
                if (ov > gv || (ov == gv && oi < gi)) { gv = ov; gi = oi; }
            }
            if (bi == gi) pv[bq] = -INFINITY;
            if (lane == 0) {
                const bool valid = (gi != 0x7fffffff);
                const float rv = (valid && gv > 0.f) ? gv : 0.f;
                valsT[r * NROWS + n] = rv;
                idxT[r * NROWS + n]  = valid ? gi : 0;
                if (valid) features[(size_t)n * DICT + gi] = rv;
            }
        }
    }
}

// ---------------------------------------------------------------------------
// Decoder: block per d, full Wd row (128KB) in LDS, 1024 threads.
// ---------------------------------------------------------------------------
__global__ __launch_bounds__(1024) void decoder_kernel(
    const float* __restrict__ Wd,
    const float* __restrict__ bd,
    const float* __restrict__ valsT,     // [KTOP][NROWS]
    const int*   __restrict__ idxT,      // [KTOP][NROWS]
    float* __restrict__ recon)
{
    __shared__ float wrow[DICT];         // 128 KB
    const int d = blockIdx.x;
    const int t = threadIdx.x;
    const float* src = Wd + (size_t)d * DICT;

    for (int i = t; i < DICT / 4; i += 1024)
        reinterpret_cast<float4*>(wrow)[i] =
            reinterpret_cast<const float4*>(src)[i];
    __syncthreads();

    const float b = bd[d];
    #pragma unroll
    for (int u = 0; u < NROWS / 1024; ++u) {
        const int n = t + 1024 * u;
        float a0 = 0.f, a1 = 0.f, a2 = 0.f, a3 = 0.f;
        #pragma unroll
        for (int k = 0; k < KTOP; k += 8) {
            float v0 = valsT[(k + 0) * NROWS + n];
            float v1 = valsT[(k + 1) * NROWS + n];
            float v2 = valsT[(k + 2) * NROWS + n];
            float v3 = valsT[(k + 3) * NROWS + n];
            float v4 = valsT[(k + 4) * NROWS + n];
            float v5 = valsT[(k + 5) * NROWS + n];
            float v6 = valsT[(k + 6) * NROWS + n];
            float v7 = valsT[(k + 7) * NROWS + n];
            int i0 = idxT[(k + 0) * NROWS + n];
            int i1 = idxT[(k + 1) * NROWS + n];
            int i2 = idxT[(k + 2) * NROWS + n];
            int i3 = idxT[(k + 3) * NROWS + n];
            int i4 = idxT[(k + 4) * NROWS + n];
            int i5 = idxT[(k + 5) * NROWS + n];
            int i6 = idxT[(k + 6) * NROWS + n];
            int i7 = idxT[(k + 7) * NROWS + n];
            a0 = fmaf(v0, wrow[i0], a0);
            a1 = fmaf(v1, wrow[i1], a1);
            a2 = fmaf(v2, wrow[i2], a2);
            a3 = fmaf(v3, wrow[i3], a3);
            a0 = fmaf(v4, wrow[i4], a0);
            a1 = fmaf(v5, wrow[i5], a1);
            a2 = fmaf(v6, wrow[i6], a2);
            a3 = fmaf(v7, wrow[i7], a3);
        }
        recon[(size_t)n * D_MODEL + d] = ((a0 + a1) + (a2 + a3)) + b;
    }
}

// ---------------------------------------------------------------------------
extern "C" void kernel_launch(void* const* d_in, const int* in_sizes, int n_in,
                              void* d_out, int out_size, void* d_ws, size_t ws_size,
                              hipStream_t stream)
{
    const float* x  = (const float*)d_in[0];
    const float* We = (const float*)d_in[1];
    const float* be = (const float*)d_in[2];
    const float* Wd = (const float*)d_in[3];
    const float* bd = (const float*)d_in[4];

    float* out      = (float*)d_out;
    float* recon    = out;
    float* features = out + (size_t)NROWS * D_MODEL;
    float* pre      = features + (size_t)NROWS * DICT;

    // bf16 tiled operands parked in the features region (memset'd after GEMM)
    unsigned short* webf = (unsigned short*)features;                 // 128 MB
    unsigned short* xbf  = webf + (size_t)TNB * NT_K * 16384;         // + 8 MB

    long cap_l = (long)(ws_size / 4 - (size_t)NROWS * (1 + 2 * KTOP)) / NROWS;
    int cap = (int)(cap_l < 64 ? 64 : (cap_l > CAPMAX ? CAPMAX : cap_l));

    char* ws = (char*)d_ws;
    int*   ws_cand  = (int*)ws;
    int*   ws_cnt   = (int*)(ws + (size_t)NROWS * cap * 4);
    float* ws_valsT = (float*)(ws + (size_t)NROWS * (cap + 1) * 4);
    int*   ws_idxT  = (int*)(ws + (size_t)NROWS * (cap + 1 + KTOP) * 4);

    // 1) convert + tile + swizzle operands to bf16
    const int conv_blocks = (int)(((size_t)NROWS * 64 + (size_t)DICT * 64) / 256);
    convert_tiles<<<conv_blocks, 256, 0, stream>>>(x, We, xbf, webf);

    // 2) encoder GEMM (256x256, 8-phase, counted vmcnt) -> approx pre_acts
    encoder_bf16<<<TMB * TNB, 512, 0, stream>>>(xbf, webf, be, pre);

    // 3) zero dense features (also wipes the bf16 staging)
    hipMemsetAsync(features, 0, (size_t)NROWS * DICT * sizeof(float), stream);

    // 4) positive-value histogram candidates
    topk_cand_hist<<<NROWS, 256, 0, stream>>>(pre, ws_cand, ws_cnt, cap);

    // 5) exact recompute + exact top-32 + scatter (transposed vals/idx out)
    recompute_select_kernel<<<NROWS, 256, 0, stream>>>(
        x, We, be, ws_cand, ws_cnt, cap, features, ws_valsT, ws_idxT);

    // 6) sparse decoder
    decoder_kernel<<<D_MODEL, 1024, 0, stream>>>(
        Wd, bd, ws_valsT, ws_idxT, recon);
}

// Round 10
// 916.518 us; speedup vs baseline: 1.9725x; 1.0723x over previous
//
#include <hip/hip_runtime.h>
#include <cstddef>
#include <cstdint>
#include <cmath>

#define D_MODEL 2048
#define DICT    32768
#define KTOP    32
#define NROWS   2048
#define NCAND_MIN 56        // candidate margin over KTOP (guards bf16 error)
#define CAPMAX  256
#define BKT     64                  // K-tile depth
#define NT_K    (D_MODEL / BKT)     // 32 K-tiles
#define TMB     (NROWS / 256)       // 8  row tiles
#define TNB     (DICT / 256)        // 128 col tiles

typedef float    f32x4  __attribute__((ext_vector_type(4)));
typedef __bf16   bf16x8 __attribute__((ext_vector_type(8)));
typedef unsigned short us8 __attribute__((ext_vector_type(8)));

__device__ __forceinline__ unsigned short f2bf_rne(float f) {
    unsigned u = __builtin_bit_cast(unsigned, f);
    unsigned r = u + 0x7fffu + ((u >> 16) & 1u);
    return (unsigned short)(r >> 16);
}

__device__ __forceinline__ void gload16(const void* g, const void* s) {
    __builtin_amdgcn_global_load_lds(
        (const __attribute__((address_space(1))) unsigned int*)g,
        (__attribute__((address_space(3))) unsigned int*)s, 16, 0, 0);
}

// ---------------------------------------------------------------------------
// Convert x and We f32 -> bf16, pre-tiled per 256-row tile into 32 K-tiles of
// 64 k. Each K-tile block = [half0(rows0-127) 16KB][half1 16KB]; within a
// half, row rloc's 128B line is chunk-permuted by byte ^= ((rloc&7)<<4) —
// the inverse of the GEMM's ds_read swizzle (gload_lds dest stays linear).
// ---------------------------------------------------------------------------
__global__ __launch_bounds__(256) void convert_tiles(
    const float* __restrict__ x,
    const float* __restrict__ We,
    unsigned short* __restrict__ xbf,     // [TMB][NT_K][16384] ushorts
    unsigned short* __restrict__ webf)    // [TNB][NT_K][16384] ushorts
{
    const size_t NX = (size_t)NROWS * 64;
    size_t id = (size_t)blockIdx.x * 256 + threadIdx.x;

    const float* src;
    unsigned short* dstb;
    int row, s;
    if (id < NX) {
        row = (int)(id >> 6); s = (int)(id & 63);
        src = x + (size_t)row * D_MODEL + s * 32;
        dstb = xbf + ((size_t)(row >> 8) * NT_K + (s >> 1)) * 16384
                   + ((row >> 7) & 1) * 8192;
    } else {
        id -= NX;
        row = (int)(id >> 6); s = (int)(id & 63);
        src = We + (size_t)row * D_MODEL + s * 32;
        dstb = webf + ((size_t)(row >> 8) * NT_K + (s >> 1)) * 16384
                    + ((row >> 7) & 1) * 8192;
    }
    const int rloc = row & 127;
    const int koff = (s & 1) * 64;

    #pragma unroll
    for (int qc = 0; qc < 4; ++qc) {
        float4 v0 = reinterpret_cast<const float4*>(src)[qc * 2];
        float4 v1 = reinterpret_cast<const float4*>(src)[qc * 2 + 1];
        us8 c;
        c[0] = f2bf_rne(v0.x); c[1] = f2bf_rne(v0.y);
        c[2] = f2bf_rne(v0.z); c[3] = f2bf_rne(v0.w);
        c[4] = f2bf_rne(v1.x); c[5] = f2bf_rne(v1.y);
        c[6] = f2bf_rne(v1.z); c[7] = f2bf_rne(v1.w);
        const int byteoff = (rloc * 128 + koff + qc * 16) ^ ((rloc & 7) << 4);
        *reinterpret_cast<us8*>(reinterpret_cast<char*>(dstb) + byteoff) = c;
    }
}

// ---------------------------------------------------------------------------
// Encoder GEMM — 8-phase schedule, deep-pipelined staging (r9 fix):
// all 4 half-tile stages of (u+2) issue at P3/P4 of tile u into buffer [cur]
// (readers drained by P2/P3), waited one FULL K-tile later via vmcnt(8) —
// 8 loads stay in flight across the tile boundary, giving every load a
// 4-5-phase (~3000 cyc) window to cover HBM latency (round-9 stall: the
// A stages had only a 2-phase window and vmcnt(4) exposed the miss).
// ---------------------------------------------------------------------------
__global__ __launch_bounds__(512, 2) void encoder_bf16(
    const unsigned short* __restrict__ xbf,
    const unsigned short* __restrict__ webf,
    const float* __restrict__ bias,
    float* __restrict__ C)
{
    __shared__ __align__(16) unsigned short Ab[2][2][8192];   // [dbuf][half]
    __shared__ __align__(16) unsigned short Bb[2][2][8192];

    const int t    = threadIdx.x;
    const int lane = t & 63;
    const int w    = t >> 6;        // 0..7
    const int wm   = w >> 2;        // 0..1  (128-row half; = A half index)
    const int wn   = w & 3;         // 0..3  (64-col slice)
    const int hB   = wn >> 1;       // B half index

    const int bid = blockIdx.x;
    const int swz = (bid & 7) * (TMB * TNB / 8) + (bid >> 3);
    const int mt  = swz & (TMB - 1);
    const int nt  = swz >> 3;

    const char* As = (const char*)xbf  + (size_t)mt * (NT_K * 32768);
    const char* Bs = (const char*)webf + (size_t)nt * (NT_K * 32768);

    f32x4 acc[8][4];
    #pragma unroll
    for (int i = 0; i < 8; ++i)
        #pragma unroll
        for (int j = 0; j < 4; ++j) acc[i][j] = (f32x4)0.f;

    const int soff = w * 2048 + lane * 16;   // byte offset in half-tile block
    const int dsti = w * 1024 + lane * 8;    // ushort idx in LDS half-buf

    #define STAGE_A(buf, u, h) do {                                          \
        const char* s_ = As + (size_t)(u) * 32768 + (h) * 16384 + soff;      \
        gload16(s_,        &Ab[buf][h][dsti]);                               \
        gload16(s_ + 1024, &Ab[buf][h][dsti + 512]);                         \
    } while (0)
    #define STAGE_B(buf, u, h) do {                                          \
        const char* s_ = Bs + (size_t)(u) * 32768 + (h) * 16384 + soff;      \
        gload16(s_,        &Bb[buf][h][dsti]);                               \
        gload16(s_ + 1024, &Bb[buf][h][dsti + 512]);                         \
    } while (0)

    bf16x8 a[4][2], b0[2][2], b1[2][2];

    #define LDA(sub) do {                                                    \
        _Pragma("unroll") for (int i = 0; i < 4; ++i)                        \
        _Pragma("unroll") for (int ks = 0; ks < 2; ++ks) {                   \
            const int rl = (sub) * 64 + i * 16 + (lane & 15);                \
            const int by = (rl * 128 + ks * 64 + ((lane >> 4) * 16))         \
                           ^ ((rl & 7) << 4);                                \
            a[i][ks] = __builtin_bit_cast(bf16x8,                            \
                *reinterpret_cast<const us8*>(                               \
                    (const char*)&Ab[cur][wm][0] + by));                     \
        } } while (0)
    #define LDB(breg, q) do {                                                \
        _Pragma("unroll") for (int j = 0; j < 2; ++j)                        \
        _Pragma("unroll") for (int ks = 0; ks < 2; ++ks) {                   \
            const int cl = (wn & 1) * 64 + (q) * 32 + j * 16 + (lane & 15);  \
            const int by = (cl * 128 + ks * 64 + ((lane >> 4) * 16))         \
                           ^ ((cl & 7) << 4);                                \
            breg[j][ks] = __builtin_bit_cast(bf16x8,                         \
                *reinterpret_cast<const us8*>(                               \
                    (const char*)&Bb[cur][hB][0] + by));                     \
        } } while (0)
    #define MMA16(ib, jb, breg) do {                                         \
        _Pragma("unroll") for (int i = 0; i < 4; ++i)                        \
        _Pragma("unroll") for (int j = 0; j < 2; ++j)                        \
        _Pragma("unroll") for (int ks = 0; ks < 2; ++ks)                     \
            acc[(ib) + i][(jb) + j] = __builtin_amdgcn_mfma_f32_16x16x32_bf16( \
                a[i][ks], breg[j][ks], acc[(ib) + i][(jb) + j], 0, 0, 0);    \
    } while (0)

    // prologue: stage tiles 0 and 1 (16 loads); retire tile 0, keep tile 1
    // in flight (vmcnt(8)) -- steady-state invariant established.
    STAGE_B(0, 0, 0); STAGE_B(0, 0, 1);
    STAGE_A(0, 0, 0); STAGE_A(0, 0, 1);
    STAGE_B(1, 1, 0); STAGE_B(1, 1, 1);
    STAGE_A(1, 1, 0); STAGE_A(1, 1, 1);
    asm volatile("s_waitcnt vmcnt(8)" ::: "memory");
    __builtin_amdgcn_sched_barrier(0);
    __builtin_amdgcn_s_barrier();

    int cur = 0;
    for (int u = 0; u < NT_K; ++u) {
        // ---- P1: ld A-sub0 (8) + B-q0 (4)
        LDA(0);
        LDB(b0, 0);
        __builtin_amdgcn_s_barrier();
        asm volatile("s_waitcnt lgkmcnt(0)" ::: "memory");
        __builtin_amdgcn_sched_barrier(0);
        __builtin_amdgcn_s_setprio(1);
        MMA16(0, 0, b0);
        __builtin_amdgcn_s_setprio(0);
        __builtin_amdgcn_s_barrier();

        // ---- P2: ld B-q1 (4)
        LDB(b1, 1);
        __builtin_amdgcn_s_barrier();
        asm volatile("s_waitcnt lgkmcnt(0)" ::: "memory");
        __builtin_amdgcn_sched_barrier(0);
        __builtin_amdgcn_s_setprio(1);
        MMA16(0, 2, b1);
        __builtin_amdgcn_s_setprio(0);
        __builtin_amdgcn_s_barrier();

        // ---- P3: ld A-sub1 (8) || stage B0(u+2) into [cur] (readers drained)
        LDA(1);
        if (u + 2 < NT_K) STAGE_B(cur, u + 2, 0);
        __builtin_amdgcn_s_barrier();
        asm volatile("s_waitcnt lgkmcnt(0)" ::: "memory");
        __builtin_amdgcn_sched_barrier(0);
        __builtin_amdgcn_s_setprio(1);
        MMA16(4, 2, b1);
        __builtin_amdgcn_s_setprio(0);
        __builtin_amdgcn_s_barrier();

        // ---- P4: stage B1(u+2)+A0(u+2)+A1(u+2); retire (u+1), keep (u+2)
        if (u + 2 < NT_K) {
            STAGE_B(cur, u + 2, 1);
            STAGE_A(cur, u + 2, 0);
            STAGE_A(cur, u + 2, 1);
            asm volatile("s_waitcnt vmcnt(8)" ::: "memory");
        } else {
            asm volatile("s_waitcnt vmcnt(0)" ::: "memory");
        }
        __builtin_amdgcn_sched_barrier(0);
        __builtin_amdgcn_s_barrier();
        __builtin_amdgcn_s_setprio(1);
        MMA16(4, 0, b0);
        __builtin_amdgcn_s_setprio(0);
        __builtin_amdgcn_s_barrier();

        cur ^= 1;
    }
    #undef STAGE_A
    #undef STAGE_B
    #undef LDA
    #undef LDB
    #undef MMA16

    const int m0 = mt * 256, n0 = nt * 256;
    #pragma unroll
    for (int j = 0; j < 4; ++j) {
        const int col = n0 + wn * 64 + j * 16 + (lane & 15);
        const float bv = bias[col];
        #pragma unroll
        for (int i = 0; i < 8; ++i) {
            const int rowb = m0 + wm * 128 + i * 16 + ((lane >> 4) * 4);
            #pragma unroll
            for (int r = 0; r < 4; ++r)
                C[(size_t)(rowb + r) * DICT + col] = acc[i][j][r] + bv;
        }
    }
}

// ---------------------------------------------------------------------------
// Histogram radix-select of positive candidates. One block per row.
// ---------------------------------------------------------------------------
__global__ __launch_bounds__(256) void topk_cand_hist(
    const float* __restrict__ pre,
    int* __restrict__ cand_idx,
    int* __restrict__ cand_cnt,
    int cap)
{
    __shared__ unsigned hist[4096];
    __shared__ unsigned part[2][256];
    __shared__ int s_thr;
    __shared__ unsigned s_cnt;

    const int n = blockIdx.x;
    const int t = threadIdx.x;
    const float4* src = reinterpret_cast<const float4*>(pre + (size_t)n * DICT);

    for (int i = t; i < 4096; i += 256) hist[i] = 0;
    if (t == 0) { s_thr = -1; s_cnt = 0; }
    __syncthreads();

    #pragma unroll 4
    for (int p = 0; p < DICT / 1024; ++p) {
        float4 v = src[t + 256 * p];
        float e[4] = {v.x, v.y, v.z, v.w};
        #pragma unroll
        for (int j = 0; j < 4; ++j)
            if (e[j] > 0.f)
                atomicAdd(&hist[__builtin_bit_cast(unsigned, e[j]) >> 19], 1u);
    }
    __syncthreads();

    unsigned hv[16];
    unsigned local = 0;
    #pragma unroll
    for (int b = 0; b < 16; ++b) { hv[b] = hist[t * 16 + b]; local += hv[b]; }
    part[0][t] = local;
    __syncthreads();
    int sb = 0;
    for (int s = 1; s < 256; s <<= 1) {
        unsigned v2 = part[sb][t];
        if (t + s < 256) v2 += part[sb][t + s];
        part[sb ^ 1][t] = v2;
        sb ^= 1;
        __syncthreads();
    }
    const unsigned above = (t < 255) ? part[sb][t + 1] : 0;

    unsigned cum = above;
    int mybin = -1;
    #pragma unroll
    for (int b = 15; b >= 0; --b) {
        cum += hv[b];
        if (mybin < 0 && cum >= NCAND_MIN) mybin = t * 16 + b;
    }
    if (mybin >= 0) atomicMax(&s_thr, mybin);
    __syncthreads();
    const unsigned thr = (s_thr < 0) ? 0u : (unsigned)s_thr;

    for (int p = 0; p < DICT / 1024; ++p) {
        float4 v = src[t + 256 * p];
        float e[4] = {v.x, v.y, v.z, v.w};
        #pragma unroll
        for (int j = 0; j < 4; ++j) {
            if (e[j] > 0.f &&
                (__builtin_bit_cast(unsigned, e[j]) >> 19) >= thr) {
                unsigned pos = atomicAdd(&s_cnt, 1u);
                if (pos < (unsigned)cap)
                    cand_idx[(size_t)n * cap + pos] = (t + 256 * p) * 4 + j;
            }
        }
    }
    __syncthreads();
    if (t == 0) cand_cnt[n] = (int)min(s_cnt, (unsigned)cap);
}

// ---------------------------------------------------------------------------
// Exact f32 recompute + exact top-32 + relu + scatter.
// Writes vals/idx in TRANSPOSED [KTOP][NROWS] layout for coalesced decoder.
// ---------------------------------------------------------------------------
__global__ __launch_bounds__(256) void recompute_select_kernel(
    const float* __restrict__ x,
    const float* __restrict__ We,
    const float* __restrict__ be,
    const int*   __restrict__ cand_idx,
    const int*   __restrict__ cand_cnt,
    int cap,
    float* __restrict__ features,
    float* __restrict__ valsT,           // [KTOP][NROWS]
    int*   __restrict__ idxT)            // [KTOP][NROWS]
{
    __shared__ float xr[D_MODEL];
    __shared__ float cv[CAPMAX];
    __shared__ int   ci[CAPMAX];

    const int n    = blockIdx.x;
    const int t    = threadIdx.x;
    const int lane = t & 63;
    const int w    = t >> 6;
    const int cnt  = cand_cnt[n];

    for (int i = t; i < D_MODEL / 4; i += 256)
        reinterpret_cast<float4*>(xr)[i] =
            reinterpret_cast<const float4*>(x + (size_t)n * D_MODEL)[i];
    for (int c = t; c < cnt; c += 256) ci[c] = cand_idx[(size_t)n * cap + c];
    __syncthreads();

    for (int c = w; c < cnt; c += 4) {
        const int idx = ci[c];
        const float4* wrow = reinterpret_cast<const float4*>(We + (size_t)idx * D_MODEL);
        const float4* xro  = reinterpret_cast<const float4*>(xr);
        float s = 0.f;
        #pragma unroll
        for (int p = 0; p < 8; ++p) {
            float4 a = xro[lane + 64 * p];
            float4 b = wrow[lane + 64 * p];
            s = fmaf(a.x, b.x, s); s = fmaf(a.y, b.y, s);
            s = fmaf(a.z, b.z, s); s = fmaf(a.w, b.w, s);
        }
        #pragma unroll
        for (int sh = 1; sh < 64; sh <<= 1) s += __shfl_xor(s, sh);
        if (lane == 0) cv[c] = s + be[idx];
    }
    __syncthreads();

    if (w == 0) {
        float pv[CAPMAX / 64];
        int   pi[CAPMAX / 64];
        #pragma unroll
        for (int qq = 0; qq < CAPMAX / 64; ++qq) {
            const int c = lane + 64 * qq;
            const bool ok = c < cnt;
            pv[qq] = ok ? cv[c] : -INFINITY;
            pi[qq] = ok ? ci[c] : 0x7fffffff;
        }
        for (int r = 0; r < KTOP; ++r) {
            float bv = pv[0]; int bi = pi[0]; int bq = 0;
            #pragma unroll
            for (int qq = 1; qq < CAPMAX / 64; ++qq)
                if (pv[qq] > bv || (pv[qq] == bv && pi[qq] < bi)) {
                    bv = pv[qq]; bi = pi[qq]; bq = qq;
                }
            float gv = bv; int gi = bi;
            #pragma unroll
            for (int s = 1; s < 64; s <<= 1) {
                float ov = __shfl_xor(gv, s);
                int   oi = __shfl_xor(gi, s);
                if (ov > gv || (ov == gv && oi < gi)) { gv = ov; gi = oi; }
            }
            if (bi == gi) pv[bq] = -INFINITY;
            if (lane == 0) {
                const bool valid = (gi != 0x7fffffff);
                const float rv = (valid && gv > 0.f) ? gv : 0.f;
                valsT[r * NROWS + n] = rv;
                idxT[r * NROWS + n]  = valid ? gi : 0;
                if (valid) features[(size_t)n * DICT + gi] = rv;
            }
        }
    }
}

// ---------------------------------------------------------------------------
// Decoder: block per d, full Wd row (128KB) in LDS, 1024 threads.
// ---------------------------------------------------------------------------
__global__ __launch_bounds__(1024) void decoder_kernel(
    const float* __restrict__ Wd,
    const float* __restrict__ bd,
    const float* __restrict__ valsT,     // [KTOP][NROWS]
    const int*   __restrict__ idxT,      // [KTOP][NROWS]
    float* __restrict__ recon)
{
    __shared__ float wrow[DICT];         // 128 KB
    const int d = blockIdx.x;
    const int t = threadIdx.x;
    const float* src = Wd + (size_t)d * DICT;

    for (int i = t; i < DICT / 4; i += 1024)
        reinterpret_cast<float4*>(wrow)[i] =
            reinterpret_cast<const float4*>(src)[i];
    __syncthreads();

    const float b = bd[d];
    #pragma unroll
    for (int u = 0; u < NROWS / 1024; ++u) {
        const int n = t + 1024 * u;
        float a0 = 0.f, a1 = 0.f, a2 = 0.f, a3 = 0.f;
        #pragma unroll
        for (int k = 0; k < KTOP; k += 8) {
            float v0 = valsT[(k + 0) * NROWS + n];
            float v1 = valsT[(k + 1) * NROWS + n];
            float v2 = valsT[(k + 2) * NROWS + n];
            float v3 = valsT[(k + 3) * NROWS + n];
            float v4 = valsT[(k + 4) * NROWS + n];
            float v5 = valsT[(k + 5) * NROWS + n];
            float v6 = valsT[(k + 6) * NROWS + n];
            float v7 = valsT[(k + 7) * NROWS + n];
            int i0 = idxT[(k + 0) * NROWS + n];
            int i1 = idxT[(k + 1) * NROWS + n];
            int i2 = idxT[(k + 2) * NROWS + n];
            int i3 = idxT[(k + 3) * NROWS + n];
            int i4 = idxT[(k + 4) * NROWS + n];
            int i5 = idxT[(k + 5) * NROWS + n];
            int i6 = idxT[(k + 6) * NROWS + n];
            int i7 = idxT[(k + 7) * NROWS + n];
            a0 = fmaf(v0, wrow[i0], a0);
            a1 = fmaf(v1, wrow[i1], a1);
            a2 = fmaf(v2, wrow[i2], a2);
            a3 = fmaf(v3, wrow[i3], a3);
            a0 = fmaf(v4, wrow[i4], a0);
            a1 = fmaf(v5, wrow[i5], a1);
            a2 = fmaf(v6, wrow[i6], a2);
            a3 = fmaf(v7, wrow[i7], a3);
        }
        recon[(size_t)n * D_MODEL + d] = ((a0 + a1) + (a2 + a3)) + b;
    }
}

// ---------------------------------------------------------------------------
extern "C" void kernel_launch(void* const* d_in, const int* in_sizes, int n_in,
                              void* d_out, int out_size, void* d_ws, size_t ws_size,
                              hipStream_t stream)
{
    const float* x  = (const float*)d_in[0];
    const float* We = (const float*)d_in[1];
    const float* be = (const float*)d_in[2];
    const float* Wd = (const float*)d_in[3];
    const float* bd = (const float*)d_in[4];

    float* out      = (float*)d_out;
    float* recon    = out;
    float* features = out + (size_t)NROWS * D_MODEL;
    float* pre      = features + (size_t)NROWS * DICT;

    // bf16 tiled operands parked in the features region (memset'd after GEMM)
    unsigned short* webf = (unsigned short*)features;                 // 128 MB
    unsigned short* xbf  = webf + (size_t)TNB * NT_K * 16384;         // + 8 MB

    long cap_l = (long)(ws_size / 4 - (size_t)NROWS * (1 + 2 * KTOP)) / NROWS;
    int cap = (int)(cap_l < 64 ? 64 : (cap_l > CAPMAX ? CAPMAX : cap_l));

    char* ws = (char*)d_ws;
    int*   ws_cand  = (int*)ws;
    int*   ws_cnt   = (int*)(ws + (size_t)NROWS * cap * 4);
    float* ws_valsT = (float*)(ws + (size_t)NROWS * (cap + 1) * 4);
    int*   ws_idxT  = (int*)(ws + (size_t)NROWS * (cap + 1 + KTOP) * 4);

    // 1) convert + tile + swizzle operands to bf16
    const int conv_blocks = (int)(((size_t)NROWS * 64 + (size_t)DICT * 64) / 256);
    convert_tiles<<<conv_blocks, 256, 0, stream>>>(x, We, xbf, webf);

    // 2) encoder GEMM (256x256, 8-phase, deep counted vmcnt) -> approx pre
    encoder_bf16<<<TMB * TNB, 512, 0, stream>>>(xbf, webf, be, pre);

    // 3) zero dense features (also wipes the bf16 staging)
    hipMemsetAsync(features, 0, (size_t)NROWS * DICT * sizeof(float), stream);

    // 4) positive-value histogram candidates
    topk_cand_hist<<<NROWS, 256, 0, stream>>>(pre, ws_cand, ws_cnt, cap);

    // 5) exact recompute + exact top-32 + scatter (transposed vals/idx out)
    recompute_select_kernel<<<NROWS, 256, 0, stream>>>(
        x, We, be, ws_cand, ws_cnt, cap, features, ws_valsT, ws_idxT);

    // 6) sparse decoder
    decoder_kernel<<<D_MODEL, 1024, 0, stream>>>(
        Wd, bd, ws_valsT, ws_idxT, recon);
}